// Round 10
// baseline (555.416 us; speedup 1.0000x reference)
//
#include <hip/hip_runtime.h>

// Gram-trick + MFMA. Ladder: 2310 -> 1380 -> 626 -> 639 -> 595 -> 555 -> 528.
// R10: sur_w co-half to grid (LDS 46.6->19KB, partial-logit atomicAdd into lgbuf);
// sur_scatter finishes softmax (bias+exp+normalize).

#define HW 16384
typedef unsigned short u16;
typedef unsigned int u32;
typedef __attribute__((ext_vector_type(8))) short short8;
typedef __attribute__((ext_vector_type(4))) float f32x4;

// staging offsets (u16 elements)
#define S_CEN 0
#define S_QW 1048576
#define S_KW 1056768
#define S_VW 1581056
#define S_W1 2105344
#define S_B1 2142208
#define S_W2 2142336
#define S_B2 2143360
#define S_SW 2143392
#define S_OW 2143400
#define S_GAMMA 2208936
#define S_BETA 2209192
#define S_TOTAL 2209456

// compact Gram layout per batch (f32 elements)
#define G_D1 0       // 128x128, stride 128
#define G_D2 16384   // 128x1024, stride 1024
#define G_S 147456   // 4 blocks of 256x256, stride 256
#define G_SZ 409600

__device__ __forceinline__ float b2f(u16 u) { return __uint_as_float(((u32)u) << 16); }
__device__ __forceinline__ u16 f2b(float f) {
  u32 u = __float_as_uint(f);
  return (u16)((u + 0x7FFFu + ((u >> 16) & 1u)) >> 16);  // RNE
}
__device__ __forceinline__ float wave_sum(float v) {
  #pragma unroll
  for (int off = 32; off > 0; off >>= 1) v += __shfl_xor(v, off, 64);
  return v;
}
__device__ __forceinline__ float wave_max(float v) {
  #pragma unroll
  for (int off = 32; off > 0; off >>= 1) v = fmaxf(v, __shfl_xor(v, off, 64));
  return v;
}
__device__ __forceinline__ void unpack8(uint4 v, float* f) {
  f[0] = __uint_as_float(v.x << 16); f[1] = __uint_as_float(v.x & 0xFFFF0000u);
  f[2] = __uint_as_float(v.y << 16); f[3] = __uint_as_float(v.y & 0xFFFF0000u);
  f[4] = __uint_as_float(v.z << 16); f[5] = __uint_as_float(v.z & 0xFFFF0000u);
  f[6] = __uint_as_float(v.w << 16); f[7] = __uint_as_float(v.w & 0xFFFF0000u);
}

// ------------------------------------------------------------ dtype probe
__global__ void probe(const u32* __restrict__ g, int* __restrict__ flag) {
  if (threadIdx.x == 0) {
    int ok = 1;
    #pragma unroll
    for (int i = 0; i < 4; i++) {
      u32 w = g[i];
      u32 lo = w & 0xFFFFu, hi = w >> 16;
      ok &= (lo >= 0x3E00u && lo <= 0x4100u) ? 1 : 0;
      ok &= (hi >= 0x3E00u && hi <= 0x4100u) ? 1 : 0;
    }
    *flag = ok ? 0 : 1;  // 0 = bf16 inputs, 1 = f32 inputs
  }
}

// ------------------------------------------------------------ stage inputs -> bf16
__global__ __launch_bounds__(256) void convert_all(
    const void* p0, const void* p1, const void* p2, const void* p3,
    const void* p4, const void* p5, const void* p6, const void* p7,
    const void* p8, const void* p9, const void* p10, const void* p11,
    u16* __restrict__ S, const int* __restrict__ flag) {
  const void* src; int n; int off;
  switch (blockIdx.z) {
    case 0:  src = p0;  n = 1048576; off = S_CEN; break;
    case 1:  src = p1;  n = 8192;    off = S_QW; break;
    case 2:  src = p2;  n = 524288;  off = S_KW; break;
    case 3:  src = p3;  n = 524288;  off = S_VW; break;
    case 4:  src = p4;  n = 36864;   off = S_W1; break;
    case 5:  src = p5;  n = 128;     off = S_B1; break;
    case 6:  src = p6;  n = 1024;    off = S_W2; break;
    case 7:  src = p7;  n = 32;      off = S_B2; break;
    case 8:  src = p8;  n = 8;       off = S_SW; break;
    case 9:  src = p9;  n = 65536;   off = S_OW; break;
    case 10: src = p10; n = 256;     off = S_GAMMA; break;
    default: src = p11; n = 256;     off = S_BETA; break;
  }
  int idx = (blockIdx.x * 256 + threadIdx.x) * 4;
  if (idx >= n) return;
  u16* dst = S + off + idx;
  if (*flag) {
    float4 v = ((const float4*)src)[idx >> 2];
    dst[0] = f2b(v.x); dst[1] = f2b(v.y); dst[2] = f2b(v.z); dst[3] = f2b(v.w);
  } else {
    *(ushort4*)dst = ((const ushort4*)src)[idx >> 2];
  }
}

// --- sur_w v4: grid (h-pair, img, co-half); partial logits atomicAdd -> lgbuf (raw)
__global__ __launch_bounds__(256) void sur_w(
    const u16* __restrict__ cen, const u16* __restrict__ w1g,
    const u16* __restrict__ b1g, const u16* __restrict__ w2g,
    float* __restrict__ lgbuf) {
  const int half = blockIdx.z;
  const int z = blockIdx.y;            // b*4+si
  const int b = z >> 2, si = z & 3, d = 1 << si;
  const int co0 = half * 16;
  __shared__ float w1s[9][32][16];     // 18 KB: only this block's co-slice
  __shared__ float w2s[8][16];
  __shared__ float b1s[16];
  const int t = threadIdx.x;
  for (int e = t; e < 4608; e += 256) {
    int tap = e >> 9, rem = e & 511, ci = rem >> 4, col = rem & 15;
    w1s[tap][ci][col] = b2f(w1g[si * 9216 + (co0 + col) * 288 + ci * 9 + tap]);
  }
  if (t < 128) w2s[t >> 4][t & 15] = b2f(w2g[si * 256 + (t >> 4) * 32 + co0 + (t & 15)]);
  if (t < 16) b1s[t] = b2f(b1g[si * 32 + co0 + t]);
  __syncthreads();

  const int px = t & 127;
  const int hh = blockIdx.x * 2 + (t >> 7);
  const int s = hh * 128 + px;
  const u16* cb = cen + (size_t)b * 32 * HW;

  float h1[16];
  #pragma unroll
  for (int i = 0; i < 16; i++) h1[i] = 0.f;
  for (int tap = 0; tap < 9; tap++) {
    int ky = tap / 3, kx = tap - ky * 3;
    int y = hh + (ky - 1) * d, x = px + (kx - 1) * d;
    if (y < 0 || y >= 128 || x < 0 || x >= 128) continue;
    int off = y * 128 + x;
    for (int ci = 0; ci < 32; ci++) {
      float v = b2f(cb[(size_t)ci * HW + off]);
      #pragma unroll
      for (int i = 0; i < 16; i++) h1[i] = fmaf(v, w1s[tap][ci][i], h1[i]);
    }
  }
  #pragma unroll
  for (int i = 0; i < 16; i++) h1[i] = fmaxf(h1[i] + b1s[i], 0.f);

  float lp[8];
  #pragma unroll
  for (int k = 0; k < 8; k++) lp[k] = 0.f;
  #pragma unroll
  for (int i = 0; i < 16; i++) {
    float v = h1[i];
    #pragma unroll
    for (int k = 0; k < 8; k++) lp[k] = fmaf(v, w2s[k][i], lp[k]);
  }
  float* dst = lgbuf + ((size_t)z * HW + s) * 8;
  #pragma unroll
  for (int k = 0; k < 8; k++) atomicAdd(&dst[k], lp[k]);
}

// --- sur_scatter v2: finish softmax (bias+exp+norm) + neighbors + sur writes
__global__ __launch_bounds__(256) void sur_scatter(
    const u16* __restrict__ cen, const float* __restrict__ lgbuf,
    const u16* __restrict__ b2g, const u16* __restrict__ swg,
    u16* __restrict__ Mbuf) {
  const int z = blockIdx.z;
  const int b = z >> 2, si = z & 3, d = 1 << si;
  const int c0 = blockIdx.y * 8;
  const int t = threadIdx.x;
  const int s = (blockIdx.x * 256 + t) * 2;  // even
  const int h = s >> 7, w = s & 127;

  float s0 = b2f(swg[si * 2 + 0]), s1 = b2f(swg[si * 2 + 1]);
  float mx = fmaxf(s0, s1);
  float e0 = expf(s0 - mx), e1 = expf(s1 - mx);
  float w20 = e0 / (e0 + e1), w21 = e1 / (e0 + e1);

  float b2s[8];
  #pragma unroll
  for (int k = 0; k < 8; k++) b2s[k] = b2f(b2g[si * 8 + k]);

  const float* lpa = lgbuf + ((size_t)z * HW + s) * 8;
  float4 la0 = *(const float4*)lpa, la1 = *(const float4*)(lpa + 4);
  float4 lb0 = *(const float4*)(lpa + 8), lb1 = *(const float4*)(lpa + 12);
  float lga[8] = {la0.x, la0.y, la0.z, la0.w, la1.x, la1.y, la1.z, la1.w};
  float lgb[8] = {lb0.x, lb0.y, lb0.z, lb0.w, lb1.x, lb1.y, lb1.z, lb1.w};
  {
    #pragma unroll
    for (int k = 0; k < 8; k++) lga[k] += b2s[k];
    float lm = lga[0];
    #pragma unroll
    for (int k = 1; k < 8; k++) lm = fmaxf(lm, lga[k]);
    float ls = 0.f;
    #pragma unroll
    for (int k = 0; k < 8; k++) { lga[k] = expf(lga[k] - lm); ls += lga[k]; }
    float inv = w20 / ls;
    #pragma unroll
    for (int k = 0; k < 8; k++) lga[k] *= inv;
  }
  {
    #pragma unroll
    for (int k = 0; k < 8; k++) lgb[k] += b2s[k];
    float lm = lgb[0];
    #pragma unroll
    for (int k = 1; k < 8; k++) lm = fmaxf(lm, lgb[k]);
    float ls = 0.f;
    #pragma unroll
    for (int k = 0; k < 8; k++) { lgb[k] = expf(lgb[k] - lm); ls += lgb[k]; }
    float inv = w20 / ls;
    #pragma unroll
    for (int k = 0; k < 8; k++) lgb[k] *= inv;
  }

  const int dy[8] = {-d, -d, -d, 0, 0, d, d, d};
  const int dx[8] = {-d, 0, d, -d, d, -d, 0, d};
  int offa[8], offb[8];
  #pragma unroll
  for (int k = 0; k < 8; k++) {
    int y = h + dy[k]; y = y < 0 ? -y : (y > 127 ? 254 - y : y);
    int xa = w + dx[k]; xa = xa < 0 ? -xa : (xa > 127 ? 254 - xa : xa);
    int xb = w + 1 + dx[k]; xb = xb < 0 ? -xb : (xb > 127 ? 254 - xb : xb);
    offa[k] = y * 128 + xa;
    offb[k] = y * 128 + xb;
  }
  const u16* cb = cen + (size_t)b * 32 * HW;
  u16* Mb = Mbuf + (size_t)b * 1152 * HW;
  for (int c = c0; c < c0 + 8; c++) {
    const u16* cc = cb + (size_t)c * HW;
    u32 cvp = *(const u32*)&cc[s];
    float cva = __uint_as_float(cvp << 16), cvb = __uint_as_float(cvp & 0xFFFF0000u);
    float nba[8], nbb[8];
    #pragma unroll
    for (int k = 0; k < 8; k++) { nba[k] = b2f(cc[offa[k]]); nbb[k] = b2f(cc[offb[k]]); }
    float sxa = 0.f, mna = 0.f, sxb = 0.f, mnb = 0.f;
    #pragma unroll
    for (int k = 0; k < 8; k++) {
      sxa = fmaf(lga[k], nba[k], sxa); mna += nba[k];
      sxb = fmaf(lgb[k], nbb[k], sxb); mnb += nbb[k];
    }
    float suma = sxa + cva * w21, sumb = sxb + cvb * w21;
    u32 cx = (u32)f2b(mna * 0.125f * w20 + cva * w21) |
             ((u32)f2b(mnb * 0.125f * w20 + cvb * w21) << 16);
    *(u32*)&Mb[(size_t)(32 * si + c) * HW + s] = cx;
    #pragma unroll
    for (int k = 0; k < 8; k++) {
      u32 pk = (u32)f2b(nba[k] - suma) | ((u32)f2b(nbb[k] - sumb) << 16);
      *(u32*)&Mb[(size_t)(128 + 256 * si + k * 32 + c) * HW + s] = pk;
    }
  }
}

// ------------ Gram via MFMA: BK=64 (4 blk/CU), 21 tiles, XCD-combo swizzle, atomics
__global__ __launch_bounds__(256) void gram_mfma(
    const u16* __restrict__ Mbuf, float* __restrict__ G) {
  const int id = blockIdx.x;
  const int tile = id >> 5, combo = id & 31;
  const int ks = combo >> 1, b = combo & 1;
  int r0, c0, gstride; size_t goff;
  if (tile == 0) { r0 = 0; c0 = 0; goff = G_D1; gstride = 128; }
  else if (tile < 9) { r0 = 0; c0 = 128 * tile; goff = G_D2 + (size_t)(tile - 1) * 128; gstride = 1024; }
  else if (tile < 17) {
    int t2 = tile - 9; int j = t2 >> 1, p = t2 & 1;
    r0 = 128 + 256 * j + 128 * p; c0 = r0;
    goff = G_S + (size_t)j * 65536 + (size_t)p * (128 * 256 + 128); gstride = 256;
  } else {
    int j = tile - 17;
    r0 = 128 + 256 * j; c0 = r0 + 128;
    goff = G_S + (size_t)j * 65536 + 128; gstride = 256;
  }
  const u16* Mb = Mbuf + (size_t)b * 1152 * HW;
  __shared__ u16 As[128][72];
  __shared__ u16 Bs[128][72];
  const int t = threadIdx.x;
  const int lane = t & 63, w = t >> 6;
  const int wr = w >> 1, wc = w & 1;
  const int m = lane & 15, quad = lane >> 4;
  f32x4 acc[4][4];
  #pragma unroll
  for (int i = 0; i < 4; i++)
    #pragma unroll
    for (int j = 0; j < 4; j++) acc[i][j] = (f32x4){0.f, 0.f, 0.f, 0.f};

  for (int s0 = ks * 1024; s0 < ks * 1024 + 1024; s0 += 64) {
    for (int e = t; e < 1024; e += 256) {
      int r = e >> 3, c8 = (e & 7) * 8;
      *(uint4*)&As[r][c8] = *(const uint4*)&Mb[(size_t)(r0 + r) * HW + s0 + c8];
      *(uint4*)&Bs[r][c8] = *(const uint4*)&Mb[(size_t)(c0 + r) * HW + s0 + c8];
    }
    __syncthreads();
    #pragma unroll
    for (int k0 = 0; k0 < 64; k0 += 32) {
      short8 af[4], bf[4];
      #pragma unroll
      for (int i = 0; i < 4; i++) af[i] = *(const short8*)&As[wr * 64 + i * 16 + m][k0 + quad * 8];
      #pragma unroll
      for (int j = 0; j < 4; j++) bf[j] = *(const short8*)&Bs[wc * 64 + j * 16 + m][k0 + quad * 8];
      #pragma unroll
      for (int i = 0; i < 4; i++)
        #pragma unroll
        for (int j = 0; j < 4; j++)
          acc[i][j] = __builtin_amdgcn_mfma_f32_16x16x32_bf16(af[i], bf[j], acc[i][j], 0, 0, 0);
    }
    __syncthreads();
  }
  float* Gb = G + (size_t)b * G_SZ + goff;
  #pragma unroll
  for (int i = 0; i < 4; i++)
    #pragma unroll
    for (int j = 0; j < 4; j++) {
      int col = wc * 64 + j * 16 + m;
      #pragma unroll
      for (int r = 0; r < 4; r++) {
        int row = wr * 64 + i * 16 + quad * 4 + r;
        atomicAdd(&Gb[(size_t)row * gstride + col], acc[i][j][r]);
      }
    }
}

// ------------------------------------- mirror S_j lower-left = upper-right^T
__global__ __launch_bounds__(256) void mirror_S(float* __restrict__ G) {
  const int j = blockIdx.x & 3, b = blockIdx.x >> 2;
  float* base = G + (size_t)b * G_SZ + G_S + (size_t)j * 65536;
  const int t = threadIdx.x;
  for (int e = t; e < 16384; e += 256) {
    int rr = e >> 7, cc = e & 127;
    base[(size_t)(128 + rr) * 256 + cc] = base[(size_t)cc * 256 + 128 + rr];
  }
}

// ------------------------------------------------------------------ Q row inv-norms
__global__ __launch_bounds__(64) void qnorm(
    const u16* __restrict__ qw, const float* __restrict__ G,
    float* __restrict__ invQ) {
  const int bn = blockIdx.x, b = bn >> 2, n = bn & 3;
  const int rq = threadIdx.x;
  const int i = rq & 3, q1r = rq >> 2;
  const u16* qr = qw + ((size_t)(i * 64) + 16 * n + q1r) * 32;
  float v[32];
  #pragma unroll
  for (int c = 0; c < 32; c++) v[c] = b2f(qr[c]);
  const float* D1 = G + (size_t)b * G_SZ;
  float ss = 0.f;
  for (int c = 0; c < 32; c++) {
    float tmp = 0.f;
    #pragma unroll
    for (int c2 = 0; c2 < 32; c2++) tmp = fmaf(v[c2], D1[(size_t)(32 * i + c2) * 128 + 32 * i + c], tmp);
    ss = fmaf(tmp, v[c], ss);
  }
  invQ[bn * 64 + rq] = 1.f / fmaxf(sqrtf(fmaxf(ss, 0.f)), 1e-12f);
}

// ------------------------------------------------------------------ K row inv-norms
__global__ __launch_bounds__(256) void knorm(
    const u16* __restrict__ kw, const float* __restrict__ G,
    float* __restrict__ invK) {
  const int rk = blockIdx.x, n = blockIdx.y, b = blockIdx.z;
  const int j = rk & 3, kk = rk >> 2;
  const u16* kr = kw + ((size_t)(j * 512) + 128 * n + kk) * 256;
  __shared__ float vs[256];
  const int t = threadIdx.x;
  vs[t] = b2f(kr[t]);
  __syncthreads();
  const float* S = G + (size_t)b * G_SZ + G_S + (size_t)j * 65536;
  float tmp = 0.f;
  for (int c2 = 0; c2 < 256; c2++) tmp = fmaf(vs[c2], S[(size_t)c2 * 256 + t], tmp);
  tmp *= vs[t];
  tmp = wave_sum(tmp);
  __shared__ float red[4];
  if ((t & 63) == 0) red[t >> 6] = tmp;
  __syncthreads();
  if (t == 0) {
    float tot = fmaxf(red[0] + red[1] + red[2] + red[3], 0.f);
    invK[(size_t)(b * 4 + n) * 512 + rk] = 1.f / fmaxf(sqrtf(tot), 1e-12f);
  }
}

// ---------- score2 (kk-split x2): per (j,half,n,b): KD = D2_j . kw_half^T, then q_w.KD
__global__ __launch_bounds__(256) void score2(
    const u16* __restrict__ qw, const u16* __restrict__ kw,
    const float* __restrict__ G, float* __restrict__ score) {
  const int jj = blockIdx.x;        // 0..7
  const int j = jj >> 1, half = jj & 1;
  const int n = blockIdx.y, b = blockIdx.z;
  const float* D2 = G + (size_t)b * G_SZ + G_D2;
  const u16* kwb = kw + ((size_t)(j * 512) + 128 * n + half * 64) * 256;  // 64 rows
  __shared__ float As[64][132];
  __shared__ u16 Bs[64][68];
  __shared__ float KD[128][68];
  __shared__ float qws[64][32];
  const int t = threadIdx.x;
  const int tx = t & 7, ty = t >> 3;
  float acc[4][8];
  #pragma unroll
  for (int i = 0; i < 4; i++)
    #pragma unroll
    for (int u = 0; u < 8; u++) acc[i][u] = 0.f;
  for (int ch0 = 0; ch0 < 256; ch0 += 64) {
    for (int e = t; e < 8192; e += 256) {
      int r = e >> 6, kc = e & 63;
      As[kc][r] = D2[(size_t)r * 1024 + j * 256 + ch0 + kc];
    }
    for (int e = t; e < 4096; e += 256) {
      int r = e >> 6, kc = e & 63;
      Bs[kc][r] = kwb[(size_t)r * 256 + ch0 + kc];
    }
    __syncthreads();
    #pragma unroll 4
    for (int kc = 0; kc < 64; kc++) {
      float a[4];
      #pragma unroll
      for (int i = 0; i < 4; i++) a[i] = As[kc][ty * 4 + i];
      float bb[8];
      #pragma unroll
      for (int u = 0; u < 8; u++) bb[u] = b2f(Bs[kc][tx * 8 + u]);
      #pragma unroll
      for (int i = 0; i < 4; i++)
        #pragma unroll
        for (int u = 0; u < 8; u++) acc[i][u] = fmaf(a[i], bb[u], acc[i][u]);
    }
    __syncthreads();
  }
  #pragma unroll
  for (int i = 0; i < 4; i++)
    #pragma unroll
    for (int u = 0; u < 8; u++) KD[ty * 4 + i][tx * 8 + u] = acc[i][u];
  for (int e = t; e < 2048; e += 256) {
    int q = e >> 5, c = e & 31;
    int i = q & 3, q1r = q >> 2;
    qws[q][c] = b2f(qw[((size_t)(i * 64) + 16 * n + q1r) * 32 + c]);
  }
  __syncthreads();
  float* sb = score + (size_t)(b * 4 + n) * 64 * 512;
  for (int e = t; e < 4096; e += 256) {
    int q = e >> 6, kkl = e & 63;
    int i = q & 3;
    float s = 0.f;
    #pragma unroll
    for (int c = 0; c < 32; c++) s = fmaf(qws[q][c], KD[i * 32 + c][kkl], s);
    sb[(size_t)q * 512 + 4 * (half * 64 + kkl) + j] = s;
  }
}

// ------------------------------------------ scale + InstanceNorm + row softmax
__global__ __launch_bounds__(256) void in_softmax(
    float* __restrict__ score, const float* __restrict__ invQ,
    const float* __restrict__ invK) {
  const int bn = blockIdx.x;
  float* sb = score + (size_t)bn * 64 * 512;
  const float* iQ = invQ + bn * 64;
  const float* iK = invK + bn * 512;
  const int t = threadIdx.x;
  float sum = 0.f, ss = 0.f;
  const float isc = 1.f / 128.f;
  for (int e = t; e < 32768; e += 256) {
    int q = e >> 9, kk = e & 511;
    float v = sb[e] * iQ[q] * iK[kk] * isc;
    sb[e] = v;
    sum += v; ss += v * v;
  }
  __shared__ float red[8];
  sum = wave_sum(sum); ss = wave_sum(ss);
  if ((t & 63) == 0) { red[t >> 6] = sum; red[4 + (t >> 6)] = ss; }
  __syncthreads();
  float mean = (red[0] + red[1] + red[2] + red[3]) * (1.f / 32768.f);
  float var = (red[4] + red[5] + red[6] + red[7]) * (1.f / 32768.f) - mean * mean;
  float istd = rsqrtf(var + 1e-5f);
  const int wv = t >> 6, lane = t & 63;
  for (int r = wv; r < 64; r += 4) {
    float z[8];
    float m = -1e30f;
    #pragma unroll
    for (int j = 0; j < 8; j++) {
      z[j] = (sb[(size_t)r * 512 + lane + 64 * j] - mean) * istd;
      m = fmaxf(m, z[j]);
    }
    m = wave_max(m);
    float sloc = 0.f;
    #pragma unroll
    for (int j = 0; j < 8; j++) { z[j] = expf(z[j] - m); sloc += z[j]; }
    sloc = wave_sum(sloc);
    float rinv = 1.f / sloc;
    #pragma unroll
    for (int j = 0; j < 8; j++) sb[(size_t)r * 512 + lane + 64 * j] = z[j] * rinv;
  }
}

// --------- attnW2 v2: grid (j*4+n, q0, b); thread = out channel; coalesced vw reads
__global__ __launch_bounds__(256) void attnW2(
    const float* __restrict__ attn, const u16* __restrict__ vw,
    float* __restrict__ W2) {
  const int j = blockIdx.x >> 2, n = blockIdx.x & 3;
  const int q0 = blockIdx.y * 8, b = blockIdx.z, bn = b * 4 + n;
  const float* ab = attn + (size_t)bn * 64 * 512;
  const int t = threadIdx.x;  // = ch 0..255
  __shared__ float at_s[8][128];
  for (int e = t; e < 1024; e += 256) {
    int qg = e >> 7, kk = e & 127;
    at_s[qg][kk] = ab[(size_t)(q0 + qg) * 512 + 4 * kk + j];
  }
  __syncthreads();
  float acc[8];
  #pragma unroll
  for (int qg = 0; qg < 8; qg++) acc[qg] = 0.f;
  const u16* vcol = vw + ((size_t)(j * 512) + 128 * n) * 256 + t;
  for (int kk = 0; kk < 128; kk++) {
    float v = b2f(vcol[(size_t)kk * 256]);
    #pragma unroll
    for (int qg = 0; qg < 8; qg++) acc[qg] = fmaf(at_s[qg][kk], v, acc[qg]);
  }
  #pragma unroll
  for (int qg = 0; qg < 8; qg++)
    W2[((size_t)bn * 64 + q0 + qg) * 1024 + j * 256 + t] = acc[qg];
}

// ------------------------------------------ Wfin16[b][o][jc] = bf16(out_w . W2)
__global__ __launch_bounds__(256) void wfin_k(
    const u16* __restrict__ ow, const float* __restrict__ W2,
    u16* __restrict__ Wfin16) {
  const int jc = blockIdx.x, b = blockIdx.y;
  __shared__ float col[256];
  const int t = threadIdx.x;
  col[t] = W2[((size_t)b * 256 + t) * 1024 + jc];
  __syncthreads();
  float acc = 0.f;
  const u16* owr = ow + (size_t)t * 256;
  for (int c = 0; c < 256; c++) acc = fmaf(b2f(owr[c]), col[c], acc);
  Wfin16[((size_t)b * 256 + t) * 1024 + jc] = f2b(acc);
}

// -------------------------------------- y = Wfin(bf16) @ sur via MFMA (bf16 out)
__global__ __launch_bounds__(256) void y_gemm_mfma(
    const u16* __restrict__ Wfin16, const u16* __restrict__ Mbuf,
    u16* __restrict__ ybuf) {
  const int b = blockIdx.z, row0 = blockIdx.y * 128, col0 = blockIdx.x * 128;
  __shared__ u16 As[128][72];
  __shared__ u16 Bs[128][72];
  const u16* Ab = Wfin16 + (size_t)b * 256 * 1024;
  const u16* Mb = Mbuf + (size_t)b * 1152 * HW + (size_t)128 * HW;
  const int t = threadIdx.x;
  const int lane = t & 63, w = t >> 6;
  const int wr = w >> 1, wc = w & 1;
  const int m = lane & 15, quad = lane >> 4;
  f32x4 acc[4][4];
  #pragma unroll
  for (int i = 0; i < 4; i++)
    #pragma unroll
    for (int j = 0; j < 4; j++) acc[i][j] = (f32x4){0.f, 0.f, 0.f, 0.f};

  for (int k0c = 0; k0c < 1024; k0c += 64) {
    for (int e = t; e < 1024; e += 256) {
      int r = e >> 3, kc8 = (e & 7) * 8;
      *(uint4*)&As[r][kc8] = *(const uint4*)&Ab[(size_t)(row0 + r) * 1024 + k0c + kc8];
    }
    for (int e = t; e < 1024; e += 256) {
      int kc = e >> 4, c8 = (e & 15) * 8;
      uint4 v = *(const uint4*)&Mb[(size_t)(k0c + kc) * HW + col0 + c8];
      u16 tmp[8]; *(uint4*)tmp = v;
      #pragma unroll
      for (int uu = 0; uu < 8; uu++) {
        int u = (uu + lane) & 7;
        Bs[c8 + u][kc] = tmp[u];
      }
    }
    __syncthreads();
    #pragma unroll
    for (int k0 = 0; k0 < 64; k0 += 32) {
      short8 af[4], bf[4];
      #pragma unroll
      for (int i = 0; i < 4; i++) af[i] = *(const short8*)&As[wr * 64 + i * 16 + m][k0 + quad * 8];
      #pragma unroll
      for (int j = 0; j < 4; j++) bf[j] = *(const short8*)&Bs[wc * 64 + j * 16 + m][k0 + quad * 8];
      #pragma unroll
      for (int i = 0; i < 4; i++)
        #pragma unroll
        for (int j = 0; j < 4; j++)
          acc[i][j] = __builtin_amdgcn_mfma_f32_16x16x32_bf16(af[i], bf[j], acc[i][j], 0, 0, 0);
    }
    __syncthreads();
  }
  #pragma unroll
  for (int i = 0; i < 4; i++)
    #pragma unroll
    for (int j = 0; j < 4; j++) {
      int col = col0 + wc * 64 + j * 16 + m;
      #pragma unroll
      for (int r = 0; r < 4; r++) {
        int row = row0 + wr * 64 + i * 16 + quad * 4 + r;
        ybuf[((size_t)b * 256 + row) * HW + col] = f2b(acc[i][j][r]);
      }
    }
}

// ---------------------------------------------------------------- BatchNorm
__global__ __launch_bounds__(256) void bn_stats(
    const u16* __restrict__ y, float* __restrict__ st) {
  const int o = blockIdx.x;
  const int t = threadIdx.x;
  float sum = 0.f, ss = 0.f;
  for (int bb = 0; bb < 2; bb++) {
    const u16* p = y + ((size_t)bb * 256 + o) * HW;
    for (int e = t; e < HW / 8; e += 256) {
      uint4 v = ((const uint4*)p)[e];
      float f[8];
      unpack8(v, f);
      #pragma unroll
      for (int k = 0; k < 8; k++) { sum += f[k]; ss += f[k] * f[k]; }
    }
  }
  __shared__ float red[8];
  sum = wave_sum(sum); ss = wave_sum(ss);
  if ((t & 63) == 0) { red[t >> 6] = sum; red[4 + (t >> 6)] = ss; }
  __syncthreads();
  if (t == 0) {
    float mean = (red[0] + red[1] + red[2] + red[3]) / 32768.f;
    float var = (red[4] + red[5] + red[6] + red[7]) / 32768.f - mean * mean;
    st[o * 2] = mean;
    st[o * 2 + 1] = rsqrtf(var + 1e-5f);
  }
}

__global__ __launch_bounds__(256) void bn_apply(
    const u16* __restrict__ y, const float* __restrict__ st,
    const u16* __restrict__ gamma, const u16* __restrict__ beta,
    const int* __restrict__ flag, void* __restrict__ out) {
  const int idx8 = blockIdx.x * 256 + threadIdx.x;
  const int r = idx8 >> 11;
  const int o = r & 255;
  float mean = st[o * 2], istd = st[o * 2 + 1];
  float g = b2f(gamma[o]), be = b2f(beta[o]);
  uint4 v = ((const uint4*)y)[idx8];
  float f[8];
  unpack8(v, f);
  float rr[8];
  #pragma unroll
  for (int k = 0; k < 8; k++) rr[k] = fmaxf((f[k] - mean) * istd * g + be, 0.f);
  if (*flag) {
    float* of = (float*)out + (size_t)idx8 * 8;
    *(float4*)of = make_float4(rr[0], rr[1], rr[2], rr[3]);
    *(float4*)(of + 4) = make_float4(rr[4], rr[5], rr[6], rr[7]);
  } else {
    u32 p0 = (u32)f2b(rr[0]) | ((u32)f2b(rr[1]) << 16);
    u32 p1 = (u32)f2b(rr[2]) | ((u32)f2b(rr[3]) << 16);
    u32 p2 = (u32)f2b(rr[4]) | ((u32)f2b(rr[5]) << 16);
    u32 p3 = (u32)f2b(rr[6]) | ((u32)f2b(rr[7]) << 16);
    ((uint4*)out)[idx8] = make_uint4(p0, p1, p2, p3);
  }
}

// ----------------------------------------------------------------------------
extern "C" void kernel_launch(void* const* d_in, const int* in_sizes, int n_in,
                              void* d_out, int out_size, void* d_ws, size_t ws_size,
                              hipStream_t stream) {
  float* G     = (float*)d_ws;           // 819,200 f32 (2 x G_SZ)
  float* score = G + 819200;             // 262,144
  float* invQ  = score + 262144;         // 512
  float* invK  = invQ + 512;             // 4,096
  float* W2    = invK + 4096;            // 524,288
  float* Wfin  = W2 + 524288;            // slot reused: u16 Wfin16
  float* bnst  = Wfin + 524288;          // 512
  int* flag    = (int*)(bnst + 512);     // 16
  u16* Sbuf    = (u16*)(flag + 16);      // S_TOTAL u16
  u16* Mbuf    = Sbuf + S_TOTAL;         // 37,748,736 u16
  u16* ybuf    = Mbuf + 37748736;        // 8,388,608 u16
  u16* Wfin16  = (u16*)Wfin;
  float* lgbuf = (float*)ybuf;           // alias: consumed before y_gemm writes ybuf

  probe<<<1, 64, 0, stream>>>((const u32*)d_in[10], flag);
  convert_all<<<dim3(1024, 1, 12), 256, 0, stream>>>(
      d_in[0], d_in[1], d_in[2], d_in[3], d_in[4], d_in[5], d_in[6], d_in[7],
      d_in[8], d_in[9], d_in[10], d_in[11], Sbuf, flag);

  hipMemsetAsync(lgbuf, 0, 4194304, stream);
  sur_w<<<dim3(64, 8, 2), 256, 0, stream>>>(
      Sbuf + S_CEN, Sbuf + S_W1, Sbuf + S_B1, Sbuf + S_W2, lgbuf);
  sur_scatter<<<dim3(32, 4, 8), 256, 0, stream>>>(
      Sbuf + S_CEN, lgbuf, Sbuf + S_B2, Sbuf + S_SW, Mbuf);
  hipMemsetAsync(G, 0, 819200 * sizeof(float), stream);
  gram_mfma<<<672, 256, 0, stream>>>(Mbuf, G);
  mirror_S<<<8, 256, 0, stream>>>(G);
  qnorm<<<8, 64, 0, stream>>>(Sbuf + S_QW, G, invQ);
  knorm<<<dim3(512, 4, 2), 256, 0, stream>>>(Sbuf + S_KW, G, invK);
  score2<<<dim3(8, 4, 2), 256, 0, stream>>>(Sbuf + S_QW, Sbuf + S_KW, G, score);
  in_softmax<<<8, 256, 0, stream>>>(score, invQ, invK);
  attnW2<<<dim3(16, 8, 2), 256, 0, stream>>>(score, Sbuf + S_VW, W2);
  wfin_k<<<dim3(1024, 2), 256, 0, stream>>>(Sbuf + S_OW, W2, Wfin16);
  y_gemm_mfma<<<dim3(128, 2, 2), 256, 0, stream>>>(Wfin16, Mbuf, ybuf);
  bn_stats<<<256, 256, 0, stream>>>(ybuf, bnst);
  bn_apply<<<4096, 256, 0, stream>>>(ybuf, bnst, Sbuf + S_GAMMA, Sbuf + S_BETA,
                                     flag, d_out);
}

// Round 11
// 514.741 us; speedup vs baseline: 1.0790x; 1.0790x over previous
//
#include <hip/hip_runtime.h>

// Gram-trick + MFMA. Ladder: 2310 -> 1380 -> 626 -> 639 -> 595 -> 555 -> 528 -> 555(R10 regress).
// R11: sur_w keeps R10's co-half-in-grid (19KB LDS) but replaces the 64MiB atomicAdd
// RMW stream with plain stores to disjoint half-slots lgbuf[z][s][half][8];
// sur_scatter sums both halves + bias. No lgbuf memset needed.

#define HW 16384
typedef unsigned short u16;
typedef unsigned int u32;
typedef __attribute__((ext_vector_type(8))) short short8;
typedef __attribute__((ext_vector_type(4))) float f32x4;

// staging offsets (u16 elements)
#define S_CEN 0
#define S_QW 1048576
#define S_KW 1056768
#define S_VW 1581056
#define S_W1 2105344
#define S_B1 2142208
#define S_W2 2142336
#define S_B2 2143360
#define S_SW 2143392
#define S_OW 2143400
#define S_GAMMA 2208936
#define S_BETA 2209192
#define S_TOTAL 2209456

// compact Gram layout per batch (f32 elements)
#define G_D1 0       // 128x128, stride 128
#define G_D2 16384   // 128x1024, stride 1024
#define G_S 147456   // 4 blocks of 256x256, stride 256
#define G_SZ 409600

__device__ __forceinline__ float b2f(u16 u) { return __uint_as_float(((u32)u) << 16); }
__device__ __forceinline__ u16 f2b(float f) {
  u32 u = __float_as_uint(f);
  return (u16)((u + 0x7FFFu + ((u >> 16) & 1u)) >> 16);  // RNE
}
__device__ __forceinline__ float wave_sum(float v) {
  #pragma unroll
  for (int off = 32; off > 0; off >>= 1) v += __shfl_xor(v, off, 64);
  return v;
}
__device__ __forceinline__ float wave_max(float v) {
  #pragma unroll
  for (int off = 32; off > 0; off >>= 1) v = fmaxf(v, __shfl_xor(v, off, 64));
  return v;
}
__device__ __forceinline__ void unpack8(uint4 v, float* f) {
  f[0] = __uint_as_float(v.x << 16); f[1] = __uint_as_float(v.x & 0xFFFF0000u);
  f[2] = __uint_as_float(v.y << 16); f[3] = __uint_as_float(v.y & 0xFFFF0000u);
  f[4] = __uint_as_float(v.z << 16); f[5] = __uint_as_float(v.z & 0xFFFF0000u);
  f[6] = __uint_as_float(v.w << 16); f[7] = __uint_as_float(v.w & 0xFFFF0000u);
}

// ------------------------------------------------------------ dtype probe
__global__ void probe(const u32* __restrict__ g, int* __restrict__ flag) {
  if (threadIdx.x == 0) {
    int ok = 1;
    #pragma unroll
    for (int i = 0; i < 4; i++) {
      u32 w = g[i];
      u32 lo = w & 0xFFFFu, hi = w >> 16;
      ok &= (lo >= 0x3E00u && lo <= 0x4100u) ? 1 : 0;
      ok &= (hi >= 0x3E00u && hi <= 0x4100u) ? 1 : 0;
    }
    *flag = ok ? 0 : 1;  // 0 = bf16 inputs, 1 = f32 inputs
  }
}

// ------------------------------------------------------------ stage inputs -> bf16
__global__ __launch_bounds__(256) void convert_all(
    const void* p0, const void* p1, const void* p2, const void* p3,
    const void* p4, const void* p5, const void* p6, const void* p7,
    const void* p8, const void* p9, const void* p10, const void* p11,
    u16* __restrict__ S, const int* __restrict__ flag) {
  const void* src; int n; int off;
  switch (blockIdx.z) {
    case 0:  src = p0;  n = 1048576; off = S_CEN; break;
    case 1:  src = p1;  n = 8192;    off = S_QW; break;
    case 2:  src = p2;  n = 524288;  off = S_KW; break;
    case 3:  src = p3;  n = 524288;  off = S_VW; break;
    case 4:  src = p4;  n = 36864;   off = S_W1; break;
    case 5:  src = p5;  n = 128;     off = S_B1; break;
    case 6:  src = p6;  n = 1024;    off = S_W2; break;
    case 7:  src = p7;  n = 32;      off = S_B2; break;
    case 8:  src = p8;  n = 8;       off = S_SW; break;
    case 9:  src = p9;  n = 65536;   off = S_OW; break;
    case 10: src = p10; n = 256;     off = S_GAMMA; break;
    default: src = p11; n = 256;     off = S_BETA; break;
  }
  int idx = (blockIdx.x * 256 + threadIdx.x) * 4;
  if (idx >= n) return;
  u16* dst = S + off + idx;
  if (*flag) {
    float4 v = ((const float4*)src)[idx >> 2];
    dst[0] = f2b(v.x); dst[1] = f2b(v.y); dst[2] = f2b(v.z); dst[3] = f2b(v.w);
  } else {
    *(ushort4*)dst = ((const ushort4*)src)[idx >> 2];
  }
}

// --- sur_w v5: grid (h-pair, img, co-half); partial logits -> lgbuf[z][s][half][8]
__global__ __launch_bounds__(256) void sur_w(
    const u16* __restrict__ cen, const u16* __restrict__ w1g,
    const u16* __restrict__ b1g, const u16* __restrict__ w2g,
    float* __restrict__ lgbuf) {
  const int half = blockIdx.z;
  const int z = blockIdx.y;            // b*4+si
  const int b = z >> 2, si = z & 3, d = 1 << si;
  const int co0 = half * 16;
  __shared__ float w1s[9][32][16];     // 18 KB: only this block's co-slice
  __shared__ float w2s[8][16];
  __shared__ float b1s[16];
  const int t = threadIdx.x;
  for (int e = t; e < 4608; e += 256) {
    int tap = e >> 9, rem = e & 511, ci = rem >> 4, col = rem & 15;
    w1s[tap][ci][col] = b2f(w1g[si * 9216 + (co0 + col) * 288 + ci * 9 + tap]);
  }
  if (t < 128) w2s[t >> 4][t & 15] = b2f(w2g[si * 256 + (t >> 4) * 32 + co0 + (t & 15)]);
  if (t < 16) b1s[t] = b2f(b1g[si * 32 + co0 + t]);
  __syncthreads();

  const int px = t & 127;
  const int hh = blockIdx.x * 2 + (t >> 7);
  const int s = hh * 128 + px;
  const u16* cb = cen + (size_t)b * 32 * HW;

  float h1[16];
  #pragma unroll
  for (int i = 0; i < 16; i++) h1[i] = 0.f;
  for (int tap = 0; tap < 9; tap++) {
    int ky = tap / 3, kx = tap - ky * 3;
    int y = hh + (ky - 1) * d, x = px + (kx - 1) * d;
    if (y < 0 || y >= 128 || x < 0 || x >= 128) continue;
    int off = y * 128 + x;
    for (int ci = 0; ci < 32; ci++) {
      float v = b2f(cb[(size_t)ci * HW + off]);
      #pragma unroll
      for (int i = 0; i < 16; i++) h1[i] = fmaf(v, w1s[tap][ci][i], h1[i]);
    }
  }
  #pragma unroll
  for (int i = 0; i < 16; i++) h1[i] = fmaxf(h1[i] + b1s[i], 0.f);

  float lp[8];
  #pragma unroll
  for (int k = 0; k < 8; k++) lp[k] = 0.f;
  #pragma unroll
  for (int i = 0; i < 16; i++) {
    float v = h1[i];
    #pragma unroll
    for (int k = 0; k < 8; k++) lp[k] = fmaf(v, w2s[k][i], lp[k]);
  }
  float* dst = lgbuf + ((size_t)z * HW + s) * 16 + half * 8;
  *(float4*)dst = make_float4(lp[0], lp[1], lp[2], lp[3]);
  *(float4*)(dst + 4) = make_float4(lp[4], lp[5], lp[6], lp[7]);
}

// --- sur_scatter v3: sum half-logits + bias, softmax, neighbors + sur writes
__global__ __launch_bounds__(256) void sur_scatter(
    const u16* __restrict__ cen, const float* __restrict__ lgbuf,
    const u16* __restrict__ b2g, const u16* __restrict__ swg,
    u16* __restrict__ Mbuf) {
  const int z = blockIdx.z;
  const int b = z >> 2, si = z & 3, d = 1 << si;
  const int c0 = blockIdx.y * 8;
  const int t = threadIdx.x;
  const int s = (blockIdx.x * 256 + t) * 2;  // even
  const int h = s >> 7, w = s & 127;

  float s0 = b2f(swg[si * 2 + 0]), s1 = b2f(swg[si * 2 + 1]);
  float mx = fmaxf(s0, s1);
  float e0 = expf(s0 - mx), e1 = expf(s1 - mx);
  float w20 = e0 / (e0 + e1), w21 = e1 / (e0 + e1);

  float b2s[8];
  #pragma unroll
  for (int k = 0; k < 8; k++) b2s[k] = b2f(b2g[si * 8 + k]);

  const float* lpa = lgbuf + ((size_t)z * HW + s) * 16;
  float lga[8], lgb[8];
  {
    float4 h0a = *(const float4*)lpa,        h0b = *(const float4*)(lpa + 4);
    float4 h1a = *(const float4*)(lpa + 8),  h1b = *(const float4*)(lpa + 12);
    lga[0] = h0a.x + h1a.x; lga[1] = h0a.y + h1a.y;
    lga[2] = h0a.z + h1a.z; lga[3] = h0a.w + h1a.w;
    lga[4] = h0b.x + h1b.x; lga[5] = h0b.y + h1b.y;
    lga[6] = h0b.z + h1b.z; lga[7] = h0b.w + h1b.w;
    float4 g0a = *(const float4*)(lpa + 16), g0b = *(const float4*)(lpa + 20);
    float4 g1a = *(const float4*)(lpa + 24), g1b = *(const float4*)(lpa + 28);
    lgb[0] = g0a.x + g1a.x; lgb[1] = g0a.y + g1a.y;
    lgb[2] = g0a.z + g1a.z; lgb[3] = g0a.w + g1a.w;
    lgb[4] = g0b.x + g1b.x; lgb[5] = g0b.y + g1b.y;
    lgb[6] = g0b.z + g1b.z; lgb[7] = g0b.w + g1b.w;
  }
  {
    #pragma unroll
    for (int k = 0; k < 8; k++) lga[k] += b2s[k];
    float lm = lga[0];
    #pragma unroll
    for (int k = 1; k < 8; k++) lm = fmaxf(lm, lga[k]);
    float ls = 0.f;
    #pragma unroll
    for (int k = 0; k < 8; k++) { lga[k] = expf(lga[k] - lm); ls += lga[k]; }
    float inv = w20 / ls;
    #pragma unroll
    for (int k = 0; k < 8; k++) lga[k] *= inv;
  }
  {
    #pragma unroll
    for (int k = 0; k < 8; k++) lgb[k] += b2s[k];
    float lm = lgb[0];
    #pragma unroll
    for (int k = 1; k < 8; k++) lm = fmaxf(lm, lgb[k]);
    float ls = 0.f;
    #pragma unroll
    for (int k = 0; k < 8; k++) { lgb[k] = expf(lgb[k] - lm); ls += lgb[k]; }
    float inv = w20 / ls;
    #pragma unroll
    for (int k = 0; k < 8; k++) lgb[k] *= inv;
  }

  const int dy[8] = {-d, -d, -d, 0, 0, d, d, d};
  const int dx[8] = {-d, 0, d, -d, d, -d, 0, d};
  int offa[8], offb[8];
  #pragma unroll
  for (int k = 0; k < 8; k++) {
    int y = h + dy[k]; y = y < 0 ? -y : (y > 127 ? 254 - y : y);
    int xa = w + dx[k]; xa = xa < 0 ? -xa : (xa > 127 ? 254 - xa : xa);
    int xb = w + 1 + dx[k]; xb = xb < 0 ? -xb : (xb > 127 ? 254 - xb : xb);
    offa[k] = y * 128 + xa;
    offb[k] = y * 128 + xb;
  }
  const u16* cb = cen + (size_t)b * 32 * HW;
  u16* Mb = Mbuf + (size_t)b * 1152 * HW;
  for (int c = c0; c < c0 + 8; c++) {
    const u16* cc = cb + (size_t)c * HW;
    u32 cvp = *(const u32*)&cc[s];
    float cva = __uint_as_float(cvp << 16), cvb = __uint_as_float(cvp & 0xFFFF0000u);
    float nba[8], nbb[8];
    #pragma unroll
    for (int k = 0; k < 8; k++) { nba[k] = b2f(cc[offa[k]]); nbb[k] = b2f(cc[offb[k]]); }
    float sxa = 0.f, mna = 0.f, sxb = 0.f, mnb = 0.f;
    #pragma unroll
    for (int k = 0; k < 8; k++) {
      sxa = fmaf(lga[k], nba[k], sxa); mna += nba[k];
      sxb = fmaf(lgb[k], nbb[k], sxb); mnb += nbb[k];
    }
    float suma = sxa + cva * w21, sumb = sxb + cvb * w21;
    u32 cx = (u32)f2b(mna * 0.125f * w20 + cva * w21) |
             ((u32)f2b(mnb * 0.125f * w20 + cvb * w21) << 16);
    *(u32*)&Mb[(size_t)(32 * si + c) * HW + s] = cx;
    #pragma unroll
    for (int k = 0; k < 8; k++) {
      u32 pk = (u32)f2b(nba[k] - suma) | ((u32)f2b(nbb[k] - sumb) << 16);
      *(u32*)&Mb[(size_t)(128 + 256 * si + k * 32 + c) * HW + s] = pk;
    }
  }
}

// ------------ Gram via MFMA: BK=64 (4 blk/CU), 21 tiles, XCD-combo swizzle, atomics
__global__ __launch_bounds__(256) void gram_mfma(
    const u16* __restrict__ Mbuf, float* __restrict__ G) {
  const int id = blockIdx.x;
  const int tile = id >> 5, combo = id & 31;
  const int ks = combo >> 1, b = combo & 1;
  int r0, c0, gstride; size_t goff;
  if (tile == 0) { r0 = 0; c0 = 0; goff = G_D1; gstride = 128; }
  else if (tile < 9) { r0 = 0; c0 = 128 * tile; goff = G_D2 + (size_t)(tile - 1) * 128; gstride = 1024; }
  else if (tile < 17) {
    int t2 = tile - 9; int j = t2 >> 1, p = t2 & 1;
    r0 = 128 + 256 * j + 128 * p; c0 = r0;
    goff = G_S + (size_t)j * 65536 + (size_t)p * (128 * 256 + 128); gstride = 256;
  } else {
    int j = tile - 17;
    r0 = 128 + 256 * j; c0 = r0 + 128;
    goff = G_S + (size_t)j * 65536 + 128; gstride = 256;
  }
  const u16* Mb = Mbuf + (size_t)b * 1152 * HW;
  __shared__ u16 As[128][72];
  __shared__ u16 Bs[128][72];
  const int t = threadIdx.x;
  const int lane = t & 63, w = t >> 6;
  const int wr = w >> 1, wc = w & 1;
  const int m = lane & 15, quad = lane >> 4;
  f32x4 acc[4][4];
  #pragma unroll
  for (int i = 0; i < 4; i++)
    #pragma unroll
    for (int j = 0; j < 4; j++) acc[i][j] = (f32x4){0.f, 0.f, 0.f, 0.f};

  for (int s0 = ks * 1024; s0 < ks * 1024 + 1024; s0 += 64) {
    for (int e = t; e < 1024; e += 256) {
      int r = e >> 3, c8 = (e & 7) * 8;
      *(uint4*)&As[r][c8] = *(const uint4*)&Mb[(size_t)(r0 + r) * HW + s0 + c8];
      *(uint4*)&Bs[r][c8] = *(const uint4*)&Mb[(size_t)(c0 + r) * HW + s0 + c8];
    }
    __syncthreads();
    #pragma unroll
    for (int k0 = 0; k0 < 64; k0 += 32) {
      short8 af[4], bf[4];
      #pragma unroll
      for (int i = 0; i < 4; i++) af[i] = *(const short8*)&As[wr * 64 + i * 16 + m][k0 + quad * 8];
      #pragma unroll
      for (int j = 0; j < 4; j++) bf[j] = *(const short8*)&Bs[wc * 64 + j * 16 + m][k0 + quad * 8];
      #pragma unroll
      for (int i = 0; i < 4; i++)
        #pragma unroll
        for (int j = 0; j < 4; j++)
          acc[i][j] = __builtin_amdgcn_mfma_f32_16x16x32_bf16(af[i], bf[j], acc[i][j], 0, 0, 0);
    }
    __syncthreads();
  }
  float* Gb = G + (size_t)b * G_SZ + goff;
  #pragma unroll
  for (int i = 0; i < 4; i++)
    #pragma unroll
    for (int j = 0; j < 4; j++) {
      int col = wc * 64 + j * 16 + m;
      #pragma unroll
      for (int r = 0; r < 4; r++) {
        int row = wr * 64 + i * 16 + quad * 4 + r;
        atomicAdd(&Gb[(size_t)row * gstride + col], acc[i][j][r]);
      }
    }
}

// ------------------------------------- mirror S_j lower-left = upper-right^T
__global__ __launch_bounds__(256) void mirror_S(float* __restrict__ G) {
  const int j = blockIdx.x & 3, b = blockIdx.x >> 2;
  float* base = G + (size_t)b * G_SZ + G_S + (size_t)j * 65536;
  const int t = threadIdx.x;
  for (int e = t; e < 16384; e += 256) {
    int rr = e >> 7, cc = e & 127;
    base[(size_t)(128 + rr) * 256 + cc] = base[(size_t)cc * 256 + 128 + rr];
  }
}

// ------------------------------------------------------------------ Q row inv-norms
__global__ __launch_bounds__(64) void qnorm(
    const u16* __restrict__ qw, const float* __restrict__ G,
    float* __restrict__ invQ) {
  const int bn = blockIdx.x, b = bn >> 2, n = bn & 3;
  const int rq = threadIdx.x;
  const int i = rq & 3, q1r = rq >> 2;
  const u16* qr = qw + ((size_t)(i * 64) + 16 * n + q1r) * 32;
  float v[32];
  #pragma unroll
  for (int c = 0; c < 32; c++) v[c] = b2f(qr[c]);
  const float* D1 = G + (size_t)b * G_SZ;
  float ss = 0.f;
  for (int c = 0; c < 32; c++) {
    float tmp = 0.f;
    #pragma unroll
    for (int c2 = 0; c2 < 32; c2++) tmp = fmaf(v[c2], D1[(size_t)(32 * i + c2) * 128 + 32 * i + c], tmp);
    ss = fmaf(tmp, v[c], ss);
  }
  invQ[bn * 64 + rq] = 1.f / fmaxf(sqrtf(fmaxf(ss, 0.f)), 1e-12f);
}

// ------------------------------------------------------------------ K row inv-norms
__global__ __launch_bounds__(256) void knorm(
    const u16* __restrict__ kw, const float* __restrict__ G,
    float* __restrict__ invK) {
  const int rk = blockIdx.x, n = blockIdx.y, b = blockIdx.z;
  const int j = rk & 3, kk = rk >> 2;
  const u16* kr = kw + ((size_t)(j * 512) + 128 * n + kk) * 256;
  __shared__ float vs[256];
  const int t = threadIdx.x;
  vs[t] = b2f(kr[t]);
  __syncthreads();
  const float* S = G + (size_t)b * G_SZ + G_S + (size_t)j * 65536;
  float tmp = 0.f;
  for (int c2 = 0; c2 < 256; c2++) tmp = fmaf(vs[c2], S[(size_t)c2 * 256 + t], tmp);
  tmp *= vs[t];
  tmp = wave_sum(tmp);
  __shared__ float red[4];
  if ((t & 63) == 0) red[t >> 6] = tmp;
  __syncthreads();
  if (t == 0) {
    float tot = fmaxf(red[0] + red[1] + red[2] + red[3], 0.f);
    invK[(size_t)(b * 4 + n) * 512 + rk] = 1.f / fmaxf(sqrtf(tot), 1e-12f);
  }
}

// ---------- score2 (kk-split x2): per (j,half,n,b): KD = D2_j . kw_half^T, then q_w.KD
__global__ __launch_bounds__(256) void score2(
    const u16* __restrict__ qw, const u16* __restrict__ kw,
    const float* __restrict__ G, float* __restrict__ score) {
  const int jj = blockIdx.x;        // 0..7
  const int j = jj >> 1, half = jj & 1;
  const int n = blockIdx.y, b = blockIdx.z;
  const float* D2 = G + (size_t)b * G_SZ + G_D2;
  const u16* kwb = kw + ((size_t)(j * 512) + 128 * n + half * 64) * 256;  // 64 rows
  __shared__ float As[64][132];
  __shared__ u16 Bs[64][68];
  __shared__ float KD[128][68];
  __shared__ float qws[64][32];
  const int t = threadIdx.x;
  const int tx = t & 7, ty = t >> 3;
  float acc[4][8];
  #pragma unroll
  for (int i = 0; i < 4; i++)
    #pragma unroll
    for (int u = 0; u < 8; u++) acc[i][u] = 0.f;
  for (int ch0 = 0; ch0 < 256; ch0 += 64) {
    for (int e = t; e < 8192; e += 256) {
      int r = e >> 6, kc = e & 63;
      As[kc][r] = D2[(size_t)r * 1024 + j * 256 + ch0 + kc];
    }
    for (int e = t; e < 4096; e += 256) {
      int r = e >> 6, kc = e & 63;
      Bs[kc][r] = kwb[(size_t)r * 256 + ch0 + kc];
    }
    __syncthreads();
    #pragma unroll 4
    for (int kc = 0; kc < 64; kc++) {
      float a[4];
      #pragma unroll
      for (int i = 0; i < 4; i++) a[i] = As[kc][ty * 4 + i];
      float bb[8];
      #pragma unroll
      for (int u = 0; u < 8; u++) bb[u] = b2f(Bs[kc][tx * 8 + u]);
      #pragma unroll
      for (int i = 0; i < 4; i++)
        #pragma unroll
        for (int u = 0; u < 8; u++) acc[i][u] = fmaf(a[i], bb[u], acc[i][u]);
    }
    __syncthreads();
  }
  #pragma unroll
  for (int i = 0; i < 4; i++)
    #pragma unroll
    for (int u = 0; u < 8; u++) KD[ty * 4 + i][tx * 8 + u] = acc[i][u];
  for (int e = t; e < 2048; e += 256) {
    int q = e >> 5, c = e & 31;
    int i = q & 3, q1r = q >> 2;
    qws[q][c] = b2f(qw[((size_t)(i * 64) + 16 * n + q1r) * 32 + c]);
  }
  __syncthreads();
  float* sb = score + (size_t)(b * 4 + n) * 64 * 512;
  for (int e = t; e < 4096; e += 256) {
    int q = e >> 6, kkl = e & 63;
    int i = q & 3;
    float s = 0.f;
    #pragma unroll
    for (int c = 0; c < 32; c++) s = fmaf(qws[q][c], KD[i * 32 + c][kkl], s);
    sb[(size_t)q * 512 + 4 * (half * 64 + kkl) + j] = s;
  }
}

// ------------------------------------------ scale + InstanceNorm + row softmax
__global__ __launch_bounds__(256) void in_softmax(
    float* __restrict__ score, const float* __restrict__ invQ,
    const float* __restrict__ invK) {
  const int bn = blockIdx.x;
  float* sb = score + (size_t)bn * 64 * 512;
  const float* iQ = invQ + bn * 64;
  const float* iK = invK + bn * 512;
  const int t = threadIdx.x;
  float sum = 0.f, ss = 0.f;
  const float isc = 1.f / 128.f;
  for (int e = t; e < 32768; e += 256) {
    int q = e >> 9, kk = e & 511;
    float v = sb[e] * iQ[q] * iK[kk] * isc;
    sb[e] = v;
    sum += v; ss += v * v;
  }
  __shared__ float red[8];
  sum = wave_sum(sum); ss = wave_sum(ss);
  if ((t & 63) == 0) { red[t >> 6] = sum; red[4 + (t >> 6)] = ss; }
  __syncthreads();
  float mean = (red[0] + red[1] + red[2] + red[3]) * (1.f / 32768.f);
  float var = (red[4] + red[5] + red[6] + red[7]) * (1.f / 32768.f) - mean * mean;
  float istd = rsqrtf(var + 1e-5f);
  const int wv = t >> 6, lane = t & 63;
  for (int r = wv; r < 64; r += 4) {
    float z[8];
    float m = -1e30f;
    #pragma unroll
    for (int j = 0; j < 8; j++) {
      z[j] = (sb[(size_t)r * 512 + lane + 64 * j] - mean) * istd;
      m = fmaxf(m, z[j]);
    }
    m = wave_max(m);
    float sloc = 0.f;
    #pragma unroll
    for (int j = 0; j < 8; j++) { z[j] = expf(z[j] - m); sloc += z[j]; }
    sloc = wave_sum(sloc);
    float rinv = 1.f / sloc;
    #pragma unroll
    for (int j = 0; j < 8; j++) sb[(size_t)r * 512 + lane + 64 * j] = z[j] * rinv;
  }
}

// --------- attnW2 v2: grid (j*4+n, q0, b); thread = out channel; coalesced vw reads
__global__ __launch_bounds__(256) void attnW2(
    const float* __restrict__ attn, const u16* __restrict__ vw,
    float* __restrict__ W2) {
  const int j = blockIdx.x >> 2, n = blockIdx.x & 3;
  const int q0 = blockIdx.y * 8, b = blockIdx.z, bn = b * 4 + n;
  const float* ab = attn + (size_t)bn * 64 * 512;
  const int t = threadIdx.x;  // = ch 0..255
  __shared__ float at_s[8][128];
  for (int e = t; e < 1024; e += 256) {
    int qg = e >> 7, kk = e & 127;
    at_s[qg][kk] = ab[(size_t)(q0 + qg) * 512 + 4 * kk + j];
  }
  __syncthreads();
  float acc[8];
  #pragma unroll
  for (int qg = 0; qg < 8; qg++) acc[qg] = 0.f;
  const u16* vcol = vw + ((size_t)(j * 512) + 128 * n) * 256 + t;
  for (int kk = 0; kk < 128; kk++) {
    float v = b2f(vcol[(size_t)kk * 256]);
    #pragma unroll
    for (int qg = 0; qg < 8; qg++) acc[qg] = fmaf(at_s[qg][kk], v, acc[qg]);
  }
  #pragma unroll
  for (int qg = 0; qg < 8; qg++)
    W2[((size_t)bn * 64 + q0 + qg) * 1024 + j * 256 + t] = acc[qg];
}

// ------------------------------------------ Wfin16[b][o][jc] = bf16(out_w . W2)
__global__ __launch_bounds__(256) void wfin_k(
    const u16* __restrict__ ow, const float* __restrict__ W2,
    u16* __restrict__ Wfin16) {
  const int jc = blockIdx.x, b = blockIdx.y;
  __shared__ float col[256];
  const int t = threadIdx.x;
  col[t] = W2[((size_t)b * 256 + t) * 1024 + jc];
  __syncthreads();
  float acc = 0.f;
  const u16* owr = ow + (size_t)t * 256;
  for (int c = 0; c < 256; c++) acc = fmaf(b2f(owr[c]), col[c], acc);
  Wfin16[((size_t)b * 256 + t) * 1024 + jc] = f2b(acc);
}

// -------------------------------------- y = Wfin(bf16) @ sur via MFMA (bf16 out)
__global__ __launch_bounds__(256) void y_gemm_mfma(
    const u16* __restrict__ Wfin16, const u16* __restrict__ Mbuf,
    u16* __restrict__ ybuf) {
  const int b = blockIdx.z, row0 = blockIdx.y * 128, col0 = blockIdx.x * 128;
  __shared__ u16 As[128][72];
  __shared__ u16 Bs[128][72];
  const u16* Ab = Wfin16 + (size_t)b * 256 * 1024;
  const u16* Mb = Mbuf + (size_t)b * 1152 * HW + (size_t)128 * HW;
  const int t = threadIdx.x;
  const int lane = t & 63, w = t >> 6;
  const int wr = w >> 1, wc = w & 1;
  const int m = lane & 15, quad = lane >> 4;
  f32x4 acc[4][4];
  #pragma unroll
  for (int i = 0; i < 4; i++)
    #pragma unroll
    for (int j = 0; j < 4; j++) acc[i][j] = (f32x4){0.f, 0.f, 0.f, 0.f};

  for (int k0c = 0; k0c < 1024; k0c += 64) {
    for (int e = t; e < 1024; e += 256) {
      int r = e >> 3, kc8 = (e & 7) * 8;
      *(uint4*)&As[r][kc8] = *(const uint4*)&Ab[(size_t)(row0 + r) * 1024 + k0c + kc8];
    }
    for (int e = t; e < 1024; e += 256) {
      int kc = e >> 4, c8 = (e & 15) * 8;
      uint4 v = *(const uint4*)&Mb[(size_t)(k0c + kc) * HW + col0 + c8];
      u16 tmp[8]; *(uint4*)tmp = v;
      #pragma unroll
      for (int uu = 0; uu < 8; uu++) {
        int u = (uu + lane) & 7;
        Bs[c8 + u][kc] = tmp[u];
      }
    }
    __syncthreads();
    #pragma unroll
    for (int k0 = 0; k0 < 64; k0 += 32) {
      short8 af[4], bf[4];
      #pragma unroll
      for (int i = 0; i < 4; i++) af[i] = *(const short8*)&As[wr * 64 + i * 16 + m][k0 + quad * 8];
      #pragma unroll
      for (int j = 0; j < 4; j++) bf[j] = *(const short8*)&Bs[wc * 64 + j * 16 + m][k0 + quad * 8];
      #pragma unroll
      for (int i = 0; i < 4; i++)
        #pragma unroll
        for (int j = 0; j < 4; j++)
          acc[i][j] = __builtin_amdgcn_mfma_f32_16x16x32_bf16(af[i], bf[j], acc[i][j], 0, 0, 0);
    }
    __syncthreads();
  }
  #pragma unroll
  for (int i = 0; i < 4; i++)
    #pragma unroll
    for (int j = 0; j < 4; j++) {
      int col = col0 + wc * 64 + j * 16 + m;
      #pragma unroll
      for (int r = 0; r < 4; r++) {
        int row = row0 + wr * 64 + i * 16 + quad * 4 + r;
        ybuf[((size_t)b * 256 + row) * HW + col] = f2b(acc[i][j][r]);
      }
    }
}

// ---------------------------------------------------------------- BatchNorm
__global__ __launch_bounds__(256) void bn_stats(
    const u16* __restrict__ y, float* __restrict__ st) {
  const int o = blockIdx.x;
  const int t = threadIdx.x;
  float sum = 0.f, ss = 0.f;
  for (int bb = 0; bb < 2; bb++) {
    const u16* p = y + ((size_t)bb * 256 + o) * HW;
    for (int e = t; e < HW / 8; e += 256) {
      uint4 v = ((const uint4*)p)[e];
      float f[8];
      unpack8(v, f);
      #pragma unroll
      for (int k = 0; k < 8; k++) { sum += f[k]; ss += f[k] * f[k]; }
    }
  }
  __shared__ float red[8];
  sum = wave_sum(sum); ss = wave_sum(ss);
  if ((t & 63) == 0) { red[t >> 6] = sum; red[4 + (t >> 6)] = ss; }
  __syncthreads();
  if (t == 0) {
    float mean = (red[0] + red[1] + red[2] + red[3]) / 32768.f;
    float var = (red[4] + red[5] + red[6] + red[7]) / 32768.f - mean * mean;
    st[o * 2] = mean;
    st[o * 2 + 1] = rsqrtf(var + 1e-5f);
  }
}

__global__ __launch_bounds__(256) void bn_apply(
    const u16* __restrict__ y, const float* __restrict__ st,
    const u16* __restrict__ gamma, const u16* __restrict__ beta,
    const int* __restrict__ flag, void* __restrict__ out) {
  const int idx8 = blockIdx.x * 256 + threadIdx.x;
  const int r = idx8 >> 11;
  const int o = r & 255;
  float mean = st[o * 2], istd = st[o * 2 + 1];
  float g = b2f(gamma[o]), be = b2f(beta[o]);
  uint4 v = ((const uint4*)y)[idx8];
  float f[8];
  unpack8(v, f);
  float rr[8];
  #pragma unroll
  for (int k = 0; k < 8; k++) rr[k] = fmaxf((f[k] - mean) * istd * g + be, 0.f);
  if (*flag) {
    float* of = (float*)out + (size_t)idx8 * 8;
    *(float4*)of = make_float4(rr[0], rr[1], rr[2], rr[3]);
    *(float4*)(of + 4) = make_float4(rr[4], rr[5], rr[6], rr[7]);
  } else {
    u32 p0 = (u32)f2b(rr[0]) | ((u32)f2b(rr[1]) << 16);
    u32 p1 = (u32)f2b(rr[2]) | ((u32)f2b(rr[3]) << 16);
    u32 p2 = (u32)f2b(rr[4]) | ((u32)f2b(rr[5]) << 16);
    u32 p3 = (u32)f2b(rr[6]) | ((u32)f2b(rr[7]) << 16);
    ((uint4*)out)[idx8] = make_uint4(p0, p1, p2, p3);
  }
}

// ----------------------------------------------------------------------------
extern "C" void kernel_launch(void* const* d_in, const int* in_sizes, int n_in,
                              void* d_out, int out_size, void* d_ws, size_t ws_size,
                              hipStream_t stream) {
  float* G     = (float*)d_ws;           // 819,200 f32 (2 x G_SZ)
  float* score = G + 819200;             // 262,144
  float* invQ  = score + 262144;         // 512
  float* invK  = invQ + 512;             // 4,096
  float* W2    = invK + 4096;            // 524,288
  float* Wfin  = W2 + 524288;            // slot reused: u16 Wfin16
  float* bnst  = Wfin + 524288;          // 512
  int* flag    = (int*)(bnst + 512);     // 16
  u16* Sbuf    = (u16*)(flag + 16);      // S_TOTAL u16
  u16* Mbuf    = Sbuf + S_TOTAL;         // 37,748,736 u16
  u16* ybuf    = Mbuf + 37748736;        // 8,388,608 u16 (16 MB)
  u16* Wfin16  = (u16*)Wfin;
  float* lgbuf = (float*)ybuf;           // alias: 8 MB [z][s][2][8], consumed before y_gemm

  probe<<<1, 64, 0, stream>>>((const u32*)d_in[10], flag);
  convert_all<<<dim3(1024, 1, 12), 256, 0, stream>>>(
      d_in[0], d_in[1], d_in[2], d_in[3], d_in[4], d_in[5], d_in[6], d_in[7],
      d_in[8], d_in[9], d_in[10], d_in[11], Sbuf, flag);

  sur_w<<<dim3(64, 8, 2), 256, 0, stream>>>(
      Sbuf + S_CEN, Sbuf + S_W1, Sbuf + S_B1, Sbuf + S_W2, lgbuf);
  sur_scatter<<<dim3(32, 4, 8), 256, 0, stream>>>(
      Sbuf + S_CEN, lgbuf, Sbuf + S_B2, Sbuf + S_SW, Mbuf);
  hipMemsetAsync(G, 0, 819200 * sizeof(float), stream);
  gram_mfma<<<672, 256, 0, stream>>>(Mbuf, G);
  mirror_S<<<8, 256, 0, stream>>>(G);
  qnorm<<<8, 64, 0, stream>>>(Sbuf + S_QW, G, invQ);
  knorm<<<dim3(512, 4, 2), 256, 0, stream>>>(Sbuf + S_KW, G, invK);
  score2<<<dim3(8, 4, 2), 256, 0, stream>>>(Sbuf + S_QW, Sbuf + S_KW, G, score);
  in_softmax<<<8, 256, 0, stream>>>(score, invQ, invK);
  attnW2<<<dim3(16, 8, 2), 256, 0, stream>>>(score, Sbuf + S_VW, W2);
  wfin_k<<<dim3(1024, 2), 256, 0, stream>>>(Sbuf + S_OW, W2, Wfin16);
  y_gemm_mfma<<<dim3(128, 2, 2), 256, 0, stream>>>(Wfin16, Mbuf, ybuf);
  bn_stats<<<256, 256, 0, stream>>>(ybuf, bnst);
  bn_apply<<<4096, 256, 0, stream>>>(ybuf, bnst, Sbuf + S_GAMMA, Sbuf + S_BETA,
                                     flag, d_out);
}

// Round 12
// 497.881 us; speedup vs baseline: 1.1156x; 1.0339x over previous
//
#include <hip/hip_runtime.h>

// Gram-trick + MFMA. Ladder: 2310 -> 1380 -> 626 -> 639 -> 595 -> 555 -> 528 -> 555 -> 514.
// R12: y_gemm v3 — 256-row x 64-col tiles (B read once), paired-k b32 transpose
// writes with bank-spreading rotation (was 4.2M conflicts, 45% VALUBusy).

#define HW 16384
typedef unsigned short u16;
typedef unsigned int u32;
typedef __attribute__((ext_vector_type(8))) short short8;
typedef __attribute__((ext_vector_type(4))) float f32x4;

// staging offsets (u16 elements)
#define S_CEN 0
#define S_QW 1048576
#define S_KW 1056768
#define S_VW 1581056
#define S_W1 2105344
#define S_B1 2142208
#define S_W2 2142336
#define S_B2 2143360
#define S_SW 2143392
#define S_OW 2143400
#define S_GAMMA 2208936
#define S_BETA 2209192
#define S_TOTAL 2209456

// compact Gram layout per batch (f32 elements)
#define G_D1 0       // 128x128, stride 128
#define G_D2 16384   // 128x1024, stride 1024
#define G_S 147456   // 4 blocks of 256x256, stride 256
#define G_SZ 409600

__device__ __forceinline__ float b2f(u16 u) { return __uint_as_float(((u32)u) << 16); }
__device__ __forceinline__ u16 f2b(float f) {
  u32 u = __float_as_uint(f);
  return (u16)((u + 0x7FFFu + ((u >> 16) & 1u)) >> 16);  // RNE
}
__device__ __forceinline__ float wave_sum(float v) {
  #pragma unroll
  for (int off = 32; off > 0; off >>= 1) v += __shfl_xor(v, off, 64);
  return v;
}
__device__ __forceinline__ float wave_max(float v) {
  #pragma unroll
  for (int off = 32; off > 0; off >>= 1) v = fmaxf(v, __shfl_xor(v, off, 64));
  return v;
}
__device__ __forceinline__ void unpack8(uint4 v, float* f) {
  f[0] = __uint_as_float(v.x << 16); f[1] = __uint_as_float(v.x & 0xFFFF0000u);
  f[2] = __uint_as_float(v.y << 16); f[3] = __uint_as_float(v.y & 0xFFFF0000u);
  f[4] = __uint_as_float(v.z << 16); f[5] = __uint_as_float(v.z & 0xFFFF0000u);
  f[6] = __uint_as_float(v.w << 16); f[7] = __uint_as_float(v.w & 0xFFFF0000u);
}

// ------------------------------------------------------------ dtype probe
__global__ void probe(const u32* __restrict__ g, int* __restrict__ flag) {
  if (threadIdx.x == 0) {
    int ok = 1;
    #pragma unroll
    for (int i = 0; i < 4; i++) {
      u32 w = g[i];
      u32 lo = w & 0xFFFFu, hi = w >> 16;
      ok &= (lo >= 0x3E00u && lo <= 0x4100u) ? 1 : 0;
      ok &= (hi >= 0x3E00u && hi <= 0x4100u) ? 1 : 0;
    }
    *flag = ok ? 0 : 1;  // 0 = bf16 inputs, 1 = f32 inputs
  }
}

// ------------------------------------------------------------ stage inputs -> bf16
__global__ __launch_bounds__(256) void convert_all(
    const void* p0, const void* p1, const void* p2, const void* p3,
    const void* p4, const void* p5, const void* p6, const void* p7,
    const void* p8, const void* p9, const void* p10, const void* p11,
    u16* __restrict__ S, const int* __restrict__ flag) {
  const void* src; int n; int off;
  switch (blockIdx.z) {
    case 0:  src = p0;  n = 1048576; off = S_CEN; break;
    case 1:  src = p1;  n = 8192;    off = S_QW; break;
    case 2:  src = p2;  n = 524288;  off = S_KW; break;
    case 3:  src = p3;  n = 524288;  off = S_VW; break;
    case 4:  src = p4;  n = 36864;   off = S_W1; break;
    case 5:  src = p5;  n = 128;     off = S_B1; break;
    case 6:  src = p6;  n = 1024;    off = S_W2; break;
    case 7:  src = p7;  n = 32;      off = S_B2; break;
    case 8:  src = p8;  n = 8;       off = S_SW; break;
    case 9:  src = p9;  n = 65536;   off = S_OW; break;
    case 10: src = p10; n = 256;     off = S_GAMMA; break;
    default: src = p11; n = 256;     off = S_BETA; break;
  }
  int idx = (blockIdx.x * 256 + threadIdx.x) * 4;
  if (idx >= n) return;
  u16* dst = S + off + idx;
  if (*flag) {
    float4 v = ((const float4*)src)[idx >> 2];
    dst[0] = f2b(v.x); dst[1] = f2b(v.y); dst[2] = f2b(v.z); dst[3] = f2b(v.w);
  } else {
    *(ushort4*)dst = ((const ushort4*)src)[idx >> 2];
  }
}

// --- sur_w v5: grid (h-pair, img, co-half); partial logits -> lgbuf[z][s][half][8]
__global__ __launch_bounds__(256) void sur_w(
    const u16* __restrict__ cen, const u16* __restrict__ w1g,
    const u16* __restrict__ b1g, const u16* __restrict__ w2g,
    float* __restrict__ lgbuf) {
  const int half = blockIdx.z;
  const int z = blockIdx.y;            // b*4+si
  const int b = z >> 2, si = z & 3, d = 1 << si;
  const int co0 = half * 16;
  __shared__ float w1s[9][32][16];     // 18 KB: only this block's co-slice
  __shared__ float w2s[8][16];
  __shared__ float b1s[16];
  const int t = threadIdx.x;
  for (int e = t; e < 4608; e += 256) {
    int tap = e >> 9, rem = e & 511, ci = rem >> 4, col = rem & 15;
    w1s[tap][ci][col] = b2f(w1g[si * 9216 + (co0 + col) * 288 + ci * 9 + tap]);
  }
  if (t < 128) w2s[t >> 4][t & 15] = b2f(w2g[si * 256 + (t >> 4) * 32 + co0 + (t & 15)]);
  if (t < 16) b1s[t] = b2f(b1g[si * 32 + co0 + t]);
  __syncthreads();

  const int px = t & 127;
  const int hh = blockIdx.x * 2 + (t >> 7);
  const int s = hh * 128 + px;
  const u16* cb = cen + (size_t)b * 32 * HW;

  float h1[16];
  #pragma unroll
  for (int i = 0; i < 16; i++) h1[i] = 0.f;
  for (int tap = 0; tap < 9; tap++) {
    int ky = tap / 3, kx = tap - ky * 3;
    int y = hh + (ky - 1) * d, x = px + (kx - 1) * d;
    if (y < 0 || y >= 128 || x < 0 || x >= 128) continue;
    int off = y * 128 + x;
    for (int ci = 0; ci < 32; ci++) {
      float v = b2f(cb[(size_t)ci * HW + off]);
      #pragma unroll
      for (int i = 0; i < 16; i++) h1[i] = fmaf(v, w1s[tap][ci][i], h1[i]);
    }
  }
  #pragma unroll
  for (int i = 0; i < 16; i++) h1[i] = fmaxf(h1[i] + b1s[i], 0.f);

  float lp[8];
  #pragma unroll
  for (int k = 0; k < 8; k++) lp[k] = 0.f;
  #pragma unroll
  for (int i = 0; i < 16; i++) {
    float v = h1[i];
    #pragma unroll
    for (int k = 0; k < 8; k++) lp[k] = fmaf(v, w2s[k][i], lp[k]);
  }
  float* dst = lgbuf + ((size_t)z * HW + s) * 16 + half * 8;
  *(float4*)dst = make_float4(lp[0], lp[1], lp[2], lp[3]);
  *(float4*)(dst + 4) = make_float4(lp[4], lp[5], lp[6], lp[7]);
}

// --- sur_scatter v3: sum half-logits + bias, softmax, neighbors + sur writes
__global__ __launch_bounds__(256) void sur_scatter(
    const u16* __restrict__ cen, const float* __restrict__ lgbuf,
    const u16* __restrict__ b2g, const u16* __restrict__ swg,
    u16* __restrict__ Mbuf) {
  const int z = blockIdx.z;
  const int b = z >> 2, si = z & 3, d = 1 << si;
  const int c0 = blockIdx.y * 8;
  const int t = threadIdx.x;
  const int s = (blockIdx.x * 256 + t) * 2;  // even
  const int h = s >> 7, w = s & 127;

  float s0 = b2f(swg[si * 2 + 0]), s1 = b2f(swg[si * 2 + 1]);
  float mx = fmaxf(s0, s1);
  float e0 = expf(s0 - mx), e1 = expf(s1 - mx);
  float w20 = e0 / (e0 + e1), w21 = e1 / (e0 + e1);

  float b2s[8];
  #pragma unroll
  for (int k = 0; k < 8; k++) b2s[k] = b2f(b2g[si * 8 + k]);

  const float* lpa = lgbuf + ((size_t)z * HW + s) * 16;
  float lga[8], lgb[8];
  {
    float4 h0a = *(const float4*)lpa,        float4_h0b = *(const float4*)(lpa + 4);
    float4 h1a = *(const float4*)(lpa + 8),  h1b = *(const float4*)(lpa + 12);
    lga[0] = h0a.x + h1a.x; lga[1] = h0a.y + h1a.y;
    lga[2] = h0a.z + h1a.z; lga[3] = h0a.w + h1a.w;
    lga[4] = float4_h0b.x + h1b.x; lga[5] = float4_h0b.y + h1b.y;
    lga[6] = float4_h0b.z + h1b.z; lga[7] = float4_h0b.w + h1b.w;
    float4 g0a = *(const float4*)(lpa + 16), g0b = *(const float4*)(lpa + 20);
    float4 g1a = *(const float4*)(lpa + 24), g1b = *(const float4*)(lpa + 28);
    lgb[0] = g0a.x + g1a.x; lgb[1] = g0a.y + g1a.y;
    lgb[2] = g0a.z + g1a.z; lgb[3] = g0a.w + g1a.w;
    lgb[4] = g0b.x + g1b.x; lgb[5] = g0b.y + g1b.y;
    lgb[6] = g0b.z + g1b.z; lgb[7] = g0b.w + g1b.w;
  }
  {
    #pragma unroll
    for (int k = 0; k < 8; k++) lga[k] += b2s[k];
    float lm = lga[0];
    #pragma unroll
    for (int k = 1; k < 8; k++) lm = fmaxf(lm, lga[k]);
    float ls = 0.f;
    #pragma unroll
    for (int k = 0; k < 8; k++) { lga[k] = expf(lga[k] - lm); ls += lga[k]; }
    float inv = w20 / ls;
    #pragma unroll
    for (int k = 0; k < 8; k++) lga[k] *= inv;
  }
  {
    #pragma unroll
    for (int k = 0; k < 8; k++) lgb[k] += b2s[k];
    float lm = lgb[0];
    #pragma unroll
    for (int k = 1; k < 8; k++) lm = fmaxf(lm, lgb[k]);
    float ls = 0.f;
    #pragma unroll
    for (int k = 0; k < 8; k++) { lgb[k] = expf(lgb[k] - lm); ls += lgb[k]; }
    float inv = w20 / ls;
    #pragma unroll
    for (int k = 0; k < 8; k++) lgb[k] *= inv;
  }

  const int dy[8] = {-d, -d, -d, 0, 0, d, d, d};
  const int dx[8] = {-d, 0, d, -d, d, -d, 0, d};
  int offa[8], offb[8];
  #pragma unroll
  for (int k = 0; k < 8; k++) {
    int y = h + dy[k]; y = y < 0 ? -y : (y > 127 ? 254 - y : y);
    int xa = w + dx[k]; xa = xa < 0 ? -xa : (xa > 127 ? 254 - xa : xa);
    int xb = w + 1 + dx[k]; xb = xb < 0 ? -xb : (xb > 127 ? 254 - xb : xb);
    offa[k] = y * 128 + xa;
    offb[k] = y * 128 + xb;
  }
  const u16* cb = cen + (size_t)b * 32 * HW;
  u16* Mb = Mbuf + (size_t)b * 1152 * HW;
  for (int c = c0; c < c0 + 8; c++) {
    const u16* cc = cb + (size_t)c * HW;
    u32 cvp = *(const u32*)&cc[s];
    float cva = __uint_as_float(cvp << 16), cvb = __uint_as_float(cvp & 0xFFFF0000u);
    float nba[8], nbb[8];
    #pragma unroll
    for (int k = 0; k < 8; k++) { nba[k] = b2f(cc[offa[k]]); nbb[k] = b2f(cc[offb[k]]); }
    float sxa = 0.f, mna = 0.f, sxb = 0.f, mnb = 0.f;
    #pragma unroll
    for (int k = 0; k < 8; k++) {
      sxa = fmaf(lga[k], nba[k], sxa); mna += nba[k];
      sxb = fmaf(lgb[k], nbb[k], sxb); mnb += nbb[k];
    }
    float suma = sxa + cva * w21, sumb = sxb + cvb * w21;
    u32 cx = (u32)f2b(mna * 0.125f * w20 + cva * w21) |
             ((u32)f2b(mnb * 0.125f * w20 + cvb * w21) << 16);
    *(u32*)&Mb[(size_t)(32 * si + c) * HW + s] = cx;
    #pragma unroll
    for (int k = 0; k < 8; k++) {
      u32 pk = (u32)f2b(nba[k] - suma) | ((u32)f2b(nbb[k] - sumb) << 16);
      *(u32*)&Mb[(size_t)(128 + 256 * si + k * 32 + c) * HW + s] = pk;
    }
  }
}

// ------------ Gram via MFMA: BK=64 (4 blk/CU), 21 tiles, XCD-combo swizzle, atomics
__global__ __launch_bounds__(256) void gram_mfma(
    const u16* __restrict__ Mbuf, float* __restrict__ G) {
  const int id = blockIdx.x;
  const int tile = id >> 5, combo = id & 31;
  const int ks = combo >> 1, b = combo & 1;
  int r0, c0, gstride; size_t goff;
  if (tile == 0) { r0 = 0; c0 = 0; goff = G_D1; gstride = 128; }
  else if (tile < 9) { r0 = 0; c0 = 128 * tile; goff = G_D2 + (size_t)(tile - 1) * 128; gstride = 1024; }
  else if (tile < 17) {
    int t2 = tile - 9; int j = t2 >> 1, p = t2 & 1;
    r0 = 128 + 256 * j + 128 * p; c0 = r0;
    goff = G_S + (size_t)j * 65536 + (size_t)p * (128 * 256 + 128); gstride = 256;
  } else {
    int j = tile - 17;
    r0 = 128 + 256 * j; c0 = r0 + 128;
    goff = G_S + (size_t)j * 65536 + 128; gstride = 256;
  }
  const u16* Mb = Mbuf + (size_t)b * 1152 * HW;
  __shared__ u16 As[128][72];
  __shared__ u16 Bs[128][72];
  const int t = threadIdx.x;
  const int lane = t & 63, w = t >> 6;
  const int wr = w >> 1, wc = w & 1;
  const int m = lane & 15, quad = lane >> 4;
  f32x4 acc[4][4];
  #pragma unroll
  for (int i = 0; i < 4; i++)
    #pragma unroll
    for (int j = 0; j < 4; j++) acc[i][j] = (f32x4){0.f, 0.f, 0.f, 0.f};

  for (int s0 = ks * 1024; s0 < ks * 1024 + 1024; s0 += 64) {
    for (int e = t; e < 1024; e += 256) {
      int r = e >> 3, c8 = (e & 7) * 8;
      *(uint4*)&As[r][c8] = *(const uint4*)&Mb[(size_t)(r0 + r) * HW + s0 + c8];
      *(uint4*)&Bs[r][c8] = *(const uint4*)&Mb[(size_t)(c0 + r) * HW + s0 + c8];
    }
    __syncthreads();
    #pragma unroll
    for (int k0 = 0; k0 < 64; k0 += 32) {
      short8 af[4], bf[4];
      #pragma unroll
      for (int i = 0; i < 4; i++) af[i] = *(const short8*)&As[wr * 64 + i * 16 + m][k0 + quad * 8];
      #pragma unroll
      for (int j = 0; j < 4; j++) bf[j] = *(const short8*)&Bs[wc * 64 + j * 16 + m][k0 + quad * 8];
      #pragma unroll
      for (int i = 0; i < 4; i++)
        #pragma unroll
        for (int j = 0; j < 4; j++)
          acc[i][j] = __builtin_amdgcn_mfma_f32_16x16x32_bf16(af[i], bf[j], acc[i][j], 0, 0, 0);
    }
    __syncthreads();
  }
  float* Gb = G + (size_t)b * G_SZ + goff;
  #pragma unroll
  for (int i = 0; i < 4; i++)
    #pragma unroll
    for (int j = 0; j < 4; j++) {
      int col = wc * 64 + j * 16 + m;
      #pragma unroll
      for (int r = 0; r < 4; r++) {
        int row = wr * 64 + i * 16 + quad * 4 + r;
        atomicAdd(&Gb[(size_t)row * gstride + col], acc[i][j][r]);
      }
    }
}

// ------------------------------------- mirror S_j lower-left = upper-right^T
__global__ __launch_bounds__(256) void mirror_S(float* __restrict__ G) {
  const int j = blockIdx.x & 3, b = blockIdx.x >> 2;
  float* base = G + (size_t)b * G_SZ + G_S + (size_t)j * 65536;
  const int t = threadIdx.x;
  for (int e = t; e < 16384; e += 256) {
    int rr = e >> 7, cc = e & 127;
    base[(size_t)(128 + rr) * 256 + cc] = base[(size_t)cc * 256 + 128 + rr];
  }
}

// ------------------------------------------------------------------ Q row inv-norms
__global__ __launch_bounds__(64) void qnorm(
    const u16* __restrict__ qw, const float* __restrict__ G,
    float* __restrict__ invQ) {
  const int bn = blockIdx.x, b = bn >> 2, n = bn & 3;
  const int rq = threadIdx.x;
  const int i = rq & 3, q1r = rq >> 2;
  const u16* qr = qw + ((size_t)(i * 64) + 16 * n + q1r) * 32;
  float v[32];
  #pragma unroll
  for (int c = 0; c < 32; c++) v[c] = b2f(qr[c]);
  const float* D1 = G + (size_t)b * G_SZ;
  float ss = 0.f;
  for (int c = 0; c < 32; c++) {
    float tmp = 0.f;
    #pragma unroll
    for (int c2 = 0; c2 < 32; c2++) tmp = fmaf(v[c2], D1[(size_t)(32 * i + c2) * 128 + 32 * i + c], tmp);
    ss = fmaf(tmp, v[c], ss);
  }
  invQ[bn * 64 + rq] = 1.f / fmaxf(sqrtf(fmaxf(ss, 0.f)), 1e-12f);
}

// ------------------------------------------------------------------ K row inv-norms
__global__ __launch_bounds__(256) void knorm(
    const u16* __restrict__ kw, const float* __restrict__ G,
    float* __restrict__ invK) {
  const int rk = blockIdx.x, n = blockIdx.y, b = blockIdx.z;
  const int j = rk & 3, kk = rk >> 2;
  const u16* kr = kw + ((size_t)(j * 512) + 128 * n + kk) * 256;
  __shared__ float vs[256];
  const int t = threadIdx.x;
  vs[t] = b2f(kr[t]);
  __syncthreads();
  const float* S = G + (size_t)b * G_SZ + G_S + (size_t)j * 65536;
  float tmp = 0.f;
  for (int c2 = 0; c2 < 256; c2++) tmp = fmaf(vs[c2], S[(size_t)c2 * 256 + t], tmp);
  tmp *= vs[t];
  tmp = wave_sum(tmp);
  __shared__ float red[4];
  if ((t & 63) == 0) red[t >> 6] = tmp;
  __syncthreads();
  if (t == 0) {
    float tot = fmaxf(red[0] + red[1] + red[2] + red[3], 0.f);
    invK[(size_t)(b * 4 + n) * 512 + rk] = 1.f / fmaxf(sqrtf(tot), 1e-12f);
  }
}

// ---------- score2 (kk-split x2): per (j,half,n,b): KD = D2_j . kw_half^T, then q_w.KD
__global__ __launch_bounds__(256) void score2(
    const u16* __restrict__ qw, const u16* __restrict__ kw,
    const float* __restrict__ G, float* __restrict__ score) {
  const int jj = blockIdx.x;        // 0..7
  const int j = jj >> 1, half = jj & 1;
  const int n = blockIdx.y, b = blockIdx.z;
  const float* D2 = G + (size_t)b * G_SZ + G_D2;
  const u16* kwb = kw + ((size_t)(j * 512) + 128 * n + half * 64) * 256;  // 64 rows
  __shared__ float As[64][132];
  __shared__ u16 Bs[64][68];
  __shared__ float KD[128][68];
  __shared__ float qws[64][32];
  const int t = threadIdx.x;
  const int tx = t & 7, ty = t >> 3;
  float acc[4][8];
  #pragma unroll
  for (int i = 0; i < 4; i++)
    #pragma unroll
    for (int u = 0; u < 8; u++) acc[i][u] = 0.f;
  for (int ch0 = 0; ch0 < 256; ch0 += 64) {
    for (int e = t; e < 8192; e += 256) {
      int r = e >> 6, kc = e & 63;
      As[kc][r] = D2[(size_t)r * 1024 + j * 256 + ch0 + kc];
    }
    for (int e = t; e < 4096; e += 256) {
      int r = e >> 6, kc = e & 63;
      Bs[kc][r] = kwb[(size_t)r * 256 + ch0 + kc];
    }
    __syncthreads();
    #pragma unroll 4
    for (int kc = 0; kc < 64; kc++) {
      float a[4];
      #pragma unroll
      for (int i = 0; i < 4; i++) a[i] = As[kc][ty * 4 + i];
      float bb[8];
      #pragma unroll
      for (int u = 0; u < 8; u++) bb[u] = b2f(Bs[kc][tx * 8 + u]);
      #pragma unroll
      for (int i = 0; i < 4; i++)
        #pragma unroll
        for (int u = 0; u < 8; u++) acc[i][u] = fmaf(a[i], bb[u], acc[i][u]);
    }
    __syncthreads();
  }
  #pragma unroll
  for (int i = 0; i < 4; i++)
    #pragma unroll
    for (int u = 0; u < 8; u++) KD[ty * 4 + i][tx * 8 + u] = acc[i][u];
  for (int e = t; e < 2048; e += 256) {
    int q = e >> 5, c = e & 31;
    int i = q & 3, q1r = q >> 2;
    qws[q][c] = b2f(qw[((size_t)(i * 64) + 16 * n + q1r) * 32 + c]);
  }
  __syncthreads();
  float* sb = score + (size_t)(b * 4 + n) * 64 * 512;
  for (int e = t; e < 4096; e += 256) {
    int q = e >> 6, kkl = e & 63;
    int i = q & 3;
    float s = 0.f;
    #pragma unroll
    for (int c = 0; c < 32; c++) s = fmaf(qws[q][c], KD[i * 32 + c][kkl], s);
    sb[(size_t)q * 512 + 4 * (half * 64 + kkl) + j] = s;
  }
}

// ------------------------------------------ scale + InstanceNorm + row softmax
__global__ __launch_bounds__(256) void in_softmax(
    float* __restrict__ score, const float* __restrict__ invQ,
    const float* __restrict__ invK) {
  const int bn = blockIdx.x;
  float* sb = score + (size_t)bn * 64 * 512;
  const float* iQ = invQ + bn * 64;
  const float* iK = invK + bn * 512;
  const int t = threadIdx.x;
  float sum = 0.f, ss = 0.f;
  const float isc = 1.f / 128.f;
  for (int e = t; e < 32768; e += 256) {
    int q = e >> 9, kk = e & 511;
    float v = sb[e] * iQ[q] * iK[kk] * isc;
    sb[e] = v;
    sum += v; ss += v * v;
  }
  __shared__ float red[8];
  sum = wave_sum(sum); ss = wave_sum(ss);
  if ((t & 63) == 0) { red[t >> 6] = sum; red[4 + (t >> 6)] = ss; }
  __syncthreads();
  float mean = (red[0] + red[1] + red[2] + red[3]) * (1.f / 32768.f);
  float var = (red[4] + red[5] + red[6] + red[7]) * (1.f / 32768.f) - mean * mean;
  float istd = rsqrtf(var + 1e-5f);
  const int wv = t >> 6, lane = t & 63;
  for (int r = wv; r < 64; r += 4) {
    float z[8];
    float m = -1e30f;
    #pragma unroll
    for (int j = 0; j < 8; j++) {
      z[j] = (sb[(size_t)r * 512 + lane + 64 * j] - mean) * istd;
      m = fmaxf(m, z[j]);
    }
    m = wave_max(m);
    float sloc = 0.f;
    #pragma unroll
    for (int j = 0; j < 8; j++) { z[j] = expf(z[j] - m); sloc += z[j]; }
    sloc = wave_sum(sloc);
    float rinv = 1.f / sloc;
    #pragma unroll
    for (int j = 0; j < 8; j++) sb[(size_t)r * 512 + lane + 64 * j] = z[j] * rinv;
  }
}

// --------- attnW2 v2: grid (j*4+n, q0, b); thread = out channel; coalesced vw reads
__global__ __launch_bounds__(256) void attnW2(
    const float* __restrict__ attn, const u16* __restrict__ vw,
    float* __restrict__ W2) {
  const int j = blockIdx.x >> 2, n = blockIdx.x & 3;
  const int q0 = blockIdx.y * 8, b = blockIdx.z, bn = b * 4 + n;
  const float* ab = attn + (size_t)bn * 64 * 512;
  const int t = threadIdx.x;  // = ch 0..255
  __shared__ float at_s[8][128];
  for (int e = t; e < 1024; e += 256) {
    int qg = e >> 7, kk = e & 127;
    at_s[qg][kk] = ab[(size_t)(q0 + qg) * 512 + 4 * kk + j];
  }
  __syncthreads();
  float acc[8];
  #pragma unroll
  for (int qg = 0; qg < 8; qg++) acc[qg] = 0.f;
  const u16* vcol = vw + ((size_t)(j * 512) + 128 * n) * 256 + t;
  for (int kk = 0; kk < 128; kk++) {
    float v = b2f(vcol[(size_t)kk * 256]);
    #pragma unroll
    for (int qg = 0; qg < 8; qg++) acc[qg] = fmaf(at_s[qg][kk], v, acc[qg]);
  }
  #pragma unroll
  for (int qg = 0; qg < 8; qg++)
    W2[((size_t)bn * 64 + q0 + qg) * 1024 + j * 256 + t] = acc[qg];
}

// ------------------------------------------ Wfin16[b][o][jc] = bf16(out_w . W2)
__global__ __launch_bounds__(256) void wfin_k(
    const u16* __restrict__ ow, const float* __restrict__ W2,
    u16* __restrict__ Wfin16) {
  const int jc = blockIdx.x, b = blockIdx.y;
  __shared__ float col[256];
  const int t = threadIdx.x;
  col[t] = W2[((size_t)b * 256 + t) * 1024 + jc];
  __syncthreads();
  float acc = 0.f;
  const u16* owr = ow + (size_t)t * 256;
  for (int c = 0; c < 256; c++) acc = fmaf(b2f(owr[c]), col[c], acc);
  Wfin16[((size_t)b * 256 + t) * 1024 + jc] = f2b(acc);
}

// ----- y_gemm v3: 256-row x 64-col tiles, B read once, paired-k b32 transpose
__global__ __launch_bounds__(256) void y_gemm_mfma(
    const u16* __restrict__ Wfin16, const u16* __restrict__ Mbuf,
    u16* __restrict__ ybuf) {
  const int b = blockIdx.y, col0 = blockIdx.x * 64;
  __shared__ u16 As[256][72];  // [o-row][k]   36 KB
  __shared__ u16 Bs[64][72];   // [s-col][k]    9 KB
  const u16* Ab = Wfin16 + (size_t)b * 256 * 1024;
  const u16* Mb = Mbuf + (size_t)b * 1152 * HW + (size_t)128 * HW;
  const int t = threadIdx.x;
  const int lane = t & 63, w = t >> 6;
  const int m = lane & 15, quad = lane >> 4;
  const int kp = t >> 3, cs = t & 7;  // B staging: k-pair 0..31, s-chunk 0..7
  f32x4 acc[4][4];
  #pragma unroll
  for (int i = 0; i < 4; i++)
    #pragma unroll
    for (int j = 0; j < 4; j++) acc[i][j] = (f32x4){0.f, 0.f, 0.f, 0.f};

  for (int k0c = 0; k0c < 1024; k0c += 64) {
    // A: 256 rows x 64 k, contiguous uint4 copies
    for (int e = t; e < 2048; e += 256) {
      int r = e >> 3, kc8 = (e & 7) * 8;
      *(uint4*)&As[r][kc8] = *(const uint4*)&Ab[(size_t)r * 1024 + k0c + kc8];
    }
    // B: 64 k x 64 s, paired-k b32 transpose writes (bank-spreading rotation)
    {
      int c8 = cs * 8;
      uint4 v0 = *(const uint4*)&Mb[(size_t)(k0c + 2 * kp) * HW + col0 + c8];
      uint4 v1 = *(const uint4*)&Mb[(size_t)(k0c + 2 * kp + 1) * HW + col0 + c8];
      u16 t0[8], t1[8];
      *(uint4*)t0 = v0; *(uint4*)t1 = v1;
      #pragma unroll
      for (int uu = 0; uu < 8; uu++) {
        int u = (uu + t) & 7;
        u32 pair = (u32)t0[u] | ((u32)t1[u] << 16);
        *(u32*)&Bs[c8 + u][2 * kp] = pair;
      }
    }
    __syncthreads();
    #pragma unroll
    for (int k0 = 0; k0 < 64; k0 += 32) {
      short8 af[4], bf[4];
      #pragma unroll
      for (int i = 0; i < 4; i++) af[i] = *(const short8*)&As[w * 64 + i * 16 + m][k0 + quad * 8];
      #pragma unroll
      for (int j = 0; j < 4; j++) bf[j] = *(const short8*)&Bs[j * 16 + m][k0 + quad * 8];
      #pragma unroll
      for (int i = 0; i < 4; i++)
        #pragma unroll
        for (int j = 0; j < 4; j++)
          acc[i][j] = __builtin_amdgcn_mfma_f32_16x16x32_bf16(af[i], bf[j], acc[i][j], 0, 0, 0);
    }
    __syncthreads();
  }
  #pragma unroll
  for (int i = 0; i < 4; i++)
    #pragma unroll
    for (int j = 0; j < 4; j++) {
      int col = col0 + j * 16 + m;
      #pragma unroll
      for (int r = 0; r < 4; r++) {
        int row = w * 64 + i * 16 + quad * 4 + r;
        ybuf[((size_t)b * 256 + row) * HW + col] = f2b(acc[i][j][r]);
      }
    }
}

// ---------------------------------------------------------------- BatchNorm
__global__ __launch_bounds__(256) void bn_stats(
    const u16* __restrict__ y, float* __restrict__ st) {
  const int o = blockIdx.x;
  const int t = threadIdx.x;
  float sum = 0.f, ss = 0.f;
  for (int bb = 0; bb < 2; bb++) {
    const u16* p = y + ((size_t)bb * 256 + o) * HW;
    for (int e = t; e < HW / 8; e += 256) {
      uint4 v = ((const uint4*)p)[e];
      float f[8];
      unpack8(v, f);
      #pragma unroll
      for (int k = 0; k < 8; k++) { sum += f[k]; ss += f[k] * f[k]; }
    }
  }
  __shared__ float red[8];
  sum = wave_sum(sum); ss = wave_sum(ss);
  if ((t & 63) == 0) { red[t >> 6] = sum; red[4 + (t >> 6)] = ss; }
  __syncthreads();
  if (t == 0) {
    float mean = (red[0] + red[1] + red[2] + red[3]) / 32768.f;
    float var = (red[4] + red[5] + red[6] + red[7]) / 32768.f - mean * mean;
    st[o * 2] = mean;
    st[o * 2 + 1] = rsqrtf(var + 1e-5f);
  }
}

__global__ __launch_bounds__(256) void bn_apply(
    const u16* __restrict__ y, const float* __restrict__ st,
    const u16* __restrict__ gamma, const u16* __restrict__ beta,
    const int* __restrict__ flag, void* __restrict__ out) {
  const int idx8 = blockIdx.x * 256 + threadIdx.x;
  const int r = idx8 >> 11;
  const int o = r & 255;
  float mean = st[o * 2], istd = st[o * 2 + 1];
  float g = b2f(gamma[o]), be = b2f(beta[o]);
  uint4 v = ((const uint4*)y)[idx8];
  float f[8];
  unpack8(v, f);
  float rr[8];
  #pragma unroll
  for (int k = 0; k < 8; k++) rr[k] = fmaxf((f[k] - mean) * istd * g + be, 0.f);
  if (*flag) {
    float* of = (float*)out + (size_t)idx8 * 8;
    *(float4*)of = make_float4(rr[0], rr[1], rr[2], rr[3]);
    *(float4*)(of + 4) = make_float4(rr[4], rr[5], rr[6], rr[7]);
  } else {
    u32 p0 = (u32)f2b(rr[0]) | ((u32)f2b(rr[1]) << 16);
    u32 p1 = (u32)f2b(rr[2]) | ((u32)f2b(rr[3]) << 16);
    u32 p2 = (u32)f2b(rr[4]) | ((u32)f2b(rr[5]) << 16);
    u32 p3 = (u32)f2b(rr[6]) | ((u32)f2b(rr[7]) << 16);
    ((uint4*)out)[idx8] = make_uint4(p0, p1, p2, p3);
  }
}

// ----------------------------------------------------------------------------
extern "C" void kernel_launch(void* const* d_in, const int* in_sizes, int n_in,
                              void* d_out, int out_size, void* d_ws, size_t ws_size,
                              hipStream_t stream) {
  float* G     = (float*)d_ws;           // 819,200 f32 (2 x G_SZ)
  float* score = G + 819200;             // 262,144
  float* invQ  = score + 262144;         // 512
  float* invK  = invQ + 512;             // 4,096
  float* W2    = invK + 4096;            // 524,288
  float* Wfin  = W2 + 524288;            // slot reused: u16 Wfin16
  float* bnst  = Wfin + 524288;          // 512
  int* flag    = (int*)(bnst + 512);     // 16
  u16* Sbuf    = (u16*)(flag + 16);      // S_TOTAL u16
  u16* Mbuf    = Sbuf + S_TOTAL;         // 37,748,736 u16
  u16* ybuf    = Mbuf + 37748736;        // 8,388,608 u16 (16 MB)
  u16* Wfin16  = (u16*)Wfin;
  float* lgbuf = (float*)ybuf;           // alias: 8 MB [z][s][2][8], consumed before y_gemm

  probe<<<1, 64, 0, stream>>>((const u32*)d_in[10], flag);
  convert_all<<<dim3(1024, 1, 12), 256, 0, stream>>>(
      d_in[0], d_in[1], d_in[2], d_in[3], d_in[4], d_in[5], d_in[6], d_in[7],
      d_in[8], d_in[9], d_in[10], d_in[11], Sbuf, flag);

  sur_w<<<dim3(64, 8, 2), 256, 0, stream>>>(
      Sbuf + S_CEN, Sbuf + S_W1, Sbuf + S_B1, Sbuf + S_W2, lgbuf);
  sur_scatter<<<dim3(32, 4, 8), 256, 0, stream>>>(
      Sbuf + S_CEN, lgbuf, Sbuf + S_B2, Sbuf + S_SW, Mbuf);
  hipMemsetAsync(G, 0, 819200 * sizeof(float), stream);
  gram_mfma<<<672, 256, 0, stream>>>(Mbuf, G);
  mirror_S<<<8, 256, 0, stream>>>(G);
  qnorm<<<8, 64, 0, stream>>>(Sbuf + S_QW, G, invQ);
  knorm<<<dim3(512, 4, 2), 256, 0, stream>>>(Sbuf + S_KW, G, invK);
  score2<<<dim3(8, 4, 2), 256, 0, stream>>>(Sbuf + S_QW, Sbuf + S_KW, G, score);
  in_softmax<<<8, 256, 0, stream>>>(score, invQ, invK);
  attnW2<<<dim3(16, 8, 2), 256, 0, stream>>>(score, Sbuf + S_VW, W2);
  wfin_k<<<dim3(1024, 2), 256, 0, stream>>>(Sbuf + S_OW, W2, Wfin16);
  y_gemm_mfma<<<dim3(256, 2), 256, 0, stream>>>(Wfin16, Mbuf, ybuf);
  bn_stats<<<256, 256, 0, stream>>>(ybuf, bnst);
  bn_apply<<<4096, 256, 0, stream>>>(ybuf, bnst, Sbuf + S_GAMMA, Sbuf + S_BETA,
                                     flag, d_out);
}